// Round 25
// baseline (362.867 us; speedup 1.0000x reference)
//
#include <hip/hip_runtime.h>
#include <math.h>

typedef __attribute__((ext_vector_type(8))) short short8m;   // 8 bf16 (4 VGPRs)
typedef __attribute__((ext_vector_type(4))) float f32x4;

__device__ inline unsigned short bf16_trunc(float f) {
  return (unsigned short)(__float_as_uint(f) >> 16);
}
__device__ inline unsigned short bf16_rte(float f) {
  unsigned u = __float_as_uint(f);
  u += 0x7fffu + ((u >> 16) & 1u);
  return (unsigned short)(u >> 16);
}
__device__ inline float bf16_tof(unsigned short h) {
  return __uint_as_float(((unsigned)h) << 16);
}
// LDS XOR-swizzle for W tiles: row pitch 128B; byte ^= ((row&7)<<4) -> conflict-free b128 r/w
__device__ inline short8m* ldsPtr(unsigned short* base, int row, int byteInRow) {
  int off = (row * 128 + byteInRow) ^ ((row & 7) << 4);
  return (short8m*)((char*)base + off);
}
__device__ inline void gload16_lds(const void* g, void* d) {
  __builtin_amdgcn_global_load_lds((const __attribute__((address_space(1))) unsigned int*)g,
                                   (__attribute__((address_space(3))) unsigned int*)d, 16, 0, 0);
}

// ---------------- conv 7x7 direct (fallback path only) ----------------
__global__ __launch_bounds__(256) void k_conv7(const float* __restrict__ x,
                                               const float* __restrict__ w,
                                               float* __restrict__ y) {
  __shared__ float ws[147];
  const int boc = blockIdx.y;
  const int oc = boc & 63;
  const int b = boc >> 6;
  for (int i = threadIdx.x; i < 147; i += 256) ws[i] = w[oc * 147 + i];
  __syncthreads();
  int px = blockIdx.x * 256 + threadIdx.x;
  if (px >= 56 * 56) return;
  int oy = px / 56, ox = px % 56;
  int iy0 = oy * 4 - 3, ix0 = ox * 4 - 3;
  float acc = 0.f;
  for (int c = 0; c < 3; ++c) {
    const float* xp = x + ((size_t)(b * 3 + c)) * 224 * 224;
    #pragma unroll
    for (int ky = 0; ky < 7; ++ky) {
      int iy = iy0 + ky;
      if ((unsigned)iy < 224u) {
        #pragma unroll
        for (int kx = 0; kx < 7; ++kx) {
          int ix = ix0 + kx;
          if ((unsigned)ix < 224u)
            acc += xp[iy * 224 + ix] * ws[c * 49 + ky * 7 + kx];
        }
      }
    }
  }
  y[((size_t)boc * 56 + oy) * 56 + ox] = fmaxf(acc, 0.f);
}

// ---------------- zero-pad weights along K ----------------
__global__ __launch_bounds__(256) void k_padw(const float* __restrict__ w,
                                              float* __restrict__ wp,
                                              int kreal, int ktot, int noc) {
  int i = blockIdx.x * 256 + threadIdx.x;
  if (i >= noc * ktot) return;
  int oc = i / ktot, k = i % ktot;
  wp[i] = (k < kreal) ? w[oc * kreal + k] : 0.f;
}

// ---------------- generic im2col + 2-plane bf16 split, block-tiled (PXT px per tile) ----
template <int CIN, int HIN, int WIN, int HOUT, int WOUT, int KH, int KW, int STR, int PAD,
          int KTOT, int PXT>
__global__ __launch_bounds__(256) void k_im2col(const float* __restrict__ x,
                                                unsigned short* __restrict__ XgH,
                                                unsigned short* __restrict__ XgM) {
  constexpr int NPX = 4 * HOUT * WOUT;
  constexpr int K8 = KTOT / 8;
  constexpr int KK = KH * KW;
  int u = blockIdx.x * 256 + threadIdx.x;
  int pxin = u % PXT;
  int rest = u / PXT;
  int k8 = rest % K8;
  int pxblk = rest / K8;
  int px = pxblk * PXT + pxin;
  if (px > NPX - 1) px = NPX - 1;          // pad replication
  const int hw = HOUT * WOUT;
  int pbv = px / hw;
  int r = px % hw;
  int py = r / WOUT, pxv = r % WOUT;
  short8m ph, pm;
  #pragma unroll
  for (int i = 0; i < 8; ++i) {
    int k = k8 * 8 + i;
    int ci = k / KK, tap = k - ci * KK;
    float v = 0.f;
    if (ci < CIN) {
      int iy = py * STR - PAD + tap / KW, ix = pxv * STR - PAD + (tap % KW);
      if ((unsigned)iy < (unsigned)HIN && (unsigned)ix < (unsigned)WIN)
        v = x[(((size_t)pbv * CIN + ci) * HIN + iy) * WIN + ix];
    }
    unsigned short hb = bf16_trunc(v);
    unsigned short mb = bf16_rte(v - bf16_tof(hb));
    ph[i] = (short)hb; pm[i] = (short)mb;
  }
  size_t off = (size_t)u * 8;
  *(short8m*)(XgH + off) = ph;
  *(short8m*)(XgM + off) = pm;
}

// ---------------- GEMM (r20-proven structure; OCT x PXT tile) ----------------
template <int COUT, int HOUT, int WOUT, int KTOT, int SPLIT, int OCT, int PXT>
__global__ __launch_bounds__(OCT * 4) void k_gemm(const unsigned short* __restrict__ XgH,
                                                  const unsigned short* __restrict__ XgM,
                                                  const float* __restrict__ wsrc,
                                                  float* __restrict__ part) {
  constexpr int NPX = 4 * HOUT * WOUT;
  constexpr int NPXB = (NPX + PXT - 1) / PXT;
  constexpr int NOCB = COUT / OCT;
  constexpr int NWG = NPXB * NOCB * SPLIT;
  constexpr int KCH = KTOT / SPLIT;
  constexpr int NCH = KCH / 64;
  constexpr int NTHR = OCT * 4;
  constexpr int NWAVE = NTHR / 64;
  constexpr int NG = PXT / 16;          // px groups per wave
  constexpr int SPP = PXT / 64;         // 64-lane slabs per koct per plane
  constexpr int TS = 16 * SPP;          // total slabs (both planes)
  constexpr int SLABSW = TS / NWAVE;    // slabs per wave
  __shared__ __align__(16) unsigned short XsH[PXT * 64];   // [8 koct][PXT px][8 k]
  __shared__ __align__(16) unsigned short XsM[PXT * 64];
  __shared__ __align__(16) unsigned short WsH[OCT * 64];   // swizzled [OCT oc][64 k]
  __shared__ __align__(16) unsigned short WsM[OCT * 64];
  __shared__ int pb[PXT], pyA[PXT], pxA[PXT];
  const int tid = threadIdx.x;
  const int flat = blockIdx.x;
  constexpr int q = NWG >> 3, r = NWG & 7;
  const int xc = flat & 7, of = flat >> 3;
  const int work = ((xc < r) ? xc * (q + 1) : r * (q + 1) + (xc - r) * q) + of;
  const int pxblk = work % NPXB;
  const int t2 = work / NPXB;
  const int oc0 = (t2 % NOCB) * OCT;
  const int spl = t2 / NOCB;
  if (tid < PXT) {
    int p = pxblk * PXT + tid;
    if (p > NPX - 1) p = NPX - 1;
    int hw = HOUT * WOUT;
    pb[tid] = p / hw;
    int rr = p % hw;
    pyA[tid] = rr / WOUT;
    pxA[tid] = rr % WOUT;
  }
  f32x4 acc[NG] = {};
  const int l = tid & 63, wv = tid >> 6;
  const int lr = l & 15, lh = l >> 4;
  __syncthreads();
  for (int ch = 0; ch < NCH; ++ch) {
    const int kbase = spl * KCH + ch * 64;
    const size_t tileOff = (size_t)pxblk * KTOT * PXT + (size_t)kbase * PXT;
    #pragma unroll
    for (int t = 0; t < SLABSW; ++t) {
      int ins = wv * SLABSW + t;
      int pl = ins >= (TS / 2);
      int wp = ins - pl * (TS / 2);
      int ko = wp / SPP, sp = wp % SPP;
      const unsigned short* g =
          (pl ? XgM : XgH) + tileOff + (size_t)ko * (PXT * 8) + sp * 512 + l * 8;
      unsigned short* d = (pl ? XsM : XsH) + ko * (PXT * 8) + sp * 512;
      gload16_lds(g, d);
    }
    #pragma unroll
    for (int j = 0; j < 2; ++j) {
      int c = tid + NTHR * j;
      int oc = c >> 3, koct = c & 7;
      const float* wp = wsrc + (size_t)(oc0 + oc) * KTOT + kbase + koct * 8;
      float vv[8];
      *(float4*)&vv[0] = *(const float4*)wp;
      *(float4*)&vv[4] = *(const float4*)(wp + 4);
      short8m ph, pm;
      #pragma unroll
      for (int i = 0; i < 8; ++i) {
        unsigned short hb = bf16_trunc(vv[i]);
        unsigned short mb = bf16_rte(vv[i] - bf16_tof(hb));
        ph[i] = (short)hb; pm[i] = (short)mb;
      }
      *ldsPtr(WsH, oc, koct * 16) = ph;
      *ldsPtr(WsM, oc, koct * 16) = pm;
    }
    __syncthreads();                       // drains vmcnt (global_load_lds) + lgkm
    #pragma unroll
    for (int ks = 0; ks < 2; ++ks) {
      const int kbyte = ks * 64 + lh * 16;
      short8m aH = *ldsPtr(WsH, wv * 16 + lr, kbyte);
      short8m aM = *ldsPtr(WsM, wv * 16 + lr, kbyte);
      const int xoff = (ks * 4 + lh) * (PXT * 8);
      #pragma unroll
      for (int g4 = 0; g4 < NG; ++g4) {
        short8m bH = *(const short8m*)(XsH + xoff + (g4 * 16 + lr) * 8);
        short8m bM = *(const short8m*)(XsM + xoff + (g4 * 16 + lr) * 8);
        acc[g4] = __builtin_amdgcn_mfma_f32_16x16x32_bf16(aH, bH, acc[g4], 0, 0, 0);
        acc[g4] = __builtin_amdgcn_mfma_f32_16x16x32_bf16(aH, bM, acc[g4], 0, 0, 0);
        acc[g4] = __builtin_amdgcn_mfma_f32_16x16x32_bf16(aM, bH, acc[g4], 0, 0, 0);
      }
    }
    __syncthreads();
  }
  const size_t N = (size_t)4 * COUT * HOUT * WOUT;
  #pragma unroll
  for (int g4 = 0; g4 < NG; ++g4) {
    int pxl = g4 * 16 + lr;
    int pidx = pxblk * PXT + pxl;
    if (pidx < NPX) {
      #pragma unroll
      for (int rr = 0; rr < 4; ++rr) {
        int ocl = wv * 16 + lh * 4 + rr;
        float v = acc[g4][rr];
        if (SPLIT == 1) v = fmaxf(v, 0.f);   // fused ReLU (direct output)
        part[(size_t)spl * N +
             (((size_t)pb[pxl] * COUT + (oc0 + ocl)) * HOUT + pyA[pxl]) * WOUT + pxA[pxl]] = v;
      }
    }
  }
}

// ---------------- split-K reduction + ReLU ----------------
template <int SPLIT>
__global__ __launch_bounds__(256) void k_red(const float* __restrict__ part,
                                             float* __restrict__ y, int n) {
  for (int i = blockIdx.x * 256 + threadIdx.x; i < n; i += gridDim.x * 256) {
    float s = 0.f;
    #pragma unroll
    for (int sp = 0; sp < SPLIT; ++sp) s += part[(size_t)sp * n + i];
    y[i] = fmaxf(s, 0.f);
  }
}

// ---------------- global-max-pool (7x7): one thread per (b,ch) ----------------
__global__ __launch_bounds__(256) void k_pool(const float* __restrict__ feat,
                                              float* __restrict__ pool) {
  int idx = blockIdx.x * 256 + threadIdx.x;
  if (idx >= 8192) return;
  const float* fp = feat + (size_t)idx * 49;
  float m = fp[0];
  #pragma unroll
  for (int i = 1; i < 49; ++i) m = fmaxf(m, fp[i]);
  pool[idx] = m;
}

// ---------------- FC(2048->14) + sigmoid: one block per (b,c) ----------------
__global__ __launch_bounds__(256) void k_fcsig(const float* __restrict__ pool,
                                               const float* __restrict__ fw,
                                               const float* __restrict__ fb,
                                               float* __restrict__ outp) {
  __shared__ float red[256];
  const int blk = blockIdx.x;       // b*14 + c
  const int b = blk / 14, c = blk % 14;
  const int tid = threadIdx.x;
  float s = 0.f;
  for (int k = tid; k < 2048; k += 256) s += pool[b * 2048 + k] * fw[c * 2048 + k];
  red[tid] = s;
  __syncthreads();
  for (int st = 128; st > 0; st >>= 1) {
    if (tid < st) red[tid] += red[tid + st];
    __syncthreads();
  }
  if (tid == 0) outp[b * 14 + c] = 1.f / (1.f + expf(-(red[0] + fb[c])));
}

// ---------------- fused FC(4096->14) + sigmoid for out_f ----------------
__global__ __launch_bounds__(256) void k_fcsig2(const float* __restrict__ poolg,
                                                const float* __restrict__ pooll,
                                                const float* __restrict__ fw,
                                                const float* __restrict__ fb,
                                                float* __restrict__ outp) {
  __shared__ float red[256];
  const int blk = blockIdx.x;       // b*14 + c
  const int b = blk / 14, c = blk % 14;
  const int tid = threadIdx.x;
  const float* w = fw + (size_t)c * 4096;
  float s = 0.f;
  for (int k = tid; k < 2048; k += 256) s += poolg[b * 2048 + k] * w[k];
  for (int k = tid; k < 2048; k += 256) s += pooll[b * 2048 + k] * w[2048 + k];
  red[tid] = s;
  __syncthreads();
  for (int st = 128; st > 0; st >>= 1) {
    if (tid < st) red[tid] += red[tid + st];
    __syncthreads();
  }
  if (tid == 0) outp[blk] = 1.f / (1.f + expf(-(red[0] + fb[c])));
}

// ---------------- loss: weighted BCEs ----------------
__global__ __launch_bounds__(64) void k_loss(const float* __restrict__ target,
                                             float* __restrict__ dout) {
  __shared__ float red[64];
  const int tid = threadIdx.x;
  float term = 0.f;
  if (tid < 56) {
    float t = target[tid];
    float pg = dout[1 + tid], plo = dout[57 + tid], pf = dout[113 + tid];
    auto bce1 = [&](float pp) {
      pp = fminf(fmaxf(pp, 1e-7f), 1.f - 1e-7f);
      return -(t * logf(pp) + (1.f - t) * log1pf(-pp));
    };
    term = (0.8f * bce1(pg) + 0.1f * bce1(plo) + 0.1f * bce1(pf)) * (1.f / 56.f);
  }
  red[tid] = term;
  __syncthreads();
  for (int st = 32; st > 0; st >>= 1) {
    if (tid < st) red[tid] += red[tid + st];
    __syncthreads();
  }
  if (tid == 0) dout[0] = red[0];
}

// ---------------- heatmap stage A: per-(b,cell) channel max|.| ----------------
__global__ __launch_bounds__(256) void k_hm7a(const float* __restrict__ feat,
                                              float* __restrict__ hmr) {
  __shared__ float red[256];
  const int b = blockIdx.x / 49, cell = blockIdx.x % 49;
  const int tid = threadIdx.x;
  float m = 0.f;
  for (int ch = tid; ch < 2048; ch += 256)
    m = fmaxf(m, fabsf(feat[((size_t)b * 2048 + ch) * 49 + cell]));
  red[tid] = m;
  __syncthreads();
  for (int st = 128; st > 0; st >>= 1) {
    if (tid < st) red[tid] = fmaxf(red[tid], red[tid + st]);
    __syncthreads();
  }
  if (tid == 0) hmr[b * 49 + cell] = red[0];
}

// ---------------- heatmap stage B: per-sample min-max normalize ----------------
__global__ __launch_bounds__(64) void k_hm7b(const float* __restrict__ hmr,
                                             float* __restrict__ hm7) {
  __shared__ float h[49];
  const int b = blockIdx.x, tid = threadIdx.x;
  if (tid < 49) h[tid] = hmr[b * 49 + tid];
  __syncthreads();
  if (tid == 0) {
    float mn = h[0], mx = h[0];
    for (int i = 1; i < 49; ++i) {
      mn = fminf(mn, h[i]);
      mx = fmaxf(mx, h[i]);
    }
    for (int i = 0; i < 49; ++i) hm7[b * 49 + i] = (h[i] - mn) / (mx - mn);
  }
}

// ---------------- parallel CCL: 1024 threads (16 waves -> 4/SIMD latency hiding) --------
#define MAXR 8
#define NRUNS (224 * MAXR)
#define CTH 1024
__global__ __launch_bounds__(CTH) void k_ccl(const float* __restrict__ hm7, float* __restrict__ bbox) {
  const int b = blockIdx.x, tid = threadIdx.x;
  __shared__ float h7[49];
  __shared__ short rx0[NRUNS], rx1[NRUNS];
  __shared__ short nr[224];
  __shared__ int lab[NRUNS];
  __shared__ int cnt[NRUNS], mid[NRUNS];
  __shared__ int rmn[NRUNS], rmx[NRUNS], cmn[NRUNS], cmx[NRUNS];
  __shared__ int chg;
  __shared__ int bestC[CTH], bestM[CTH], bestI[CTH];

  if (tid < 49) h7[tid] = hm7[b * 49 + tid];
  for (int i = tid; i < NRUNS; i += CTH) {
    cnt[i] = 0; mid[i] = -1;
    rmn[i] = 1 << 30; rmx[i] = -1; cmn[i] = 1 << 30; cmx[i] = -1;
    lab[i] = i;
  }
  __syncthreads();
  if (tid < 224) {
    int yy = tid;
    float py = ((float)yy + 0.5f) * (7.f / 224.f) - 0.5f;
    py = fminf(fmaxf(py, 0.f), 6.f);
    int y0 = (int)floorf(py);
    if (y0 > 5) y0 = 5;
    float fy = py - (float)y0;
    int n = 0, start = -1;
    const int segLo[6] = {0, 48, 80, 112, 144, 176};
    const int segHi[6] = {48, 80, 112, 144, 176, 224};
    #pragma unroll
    for (int s = 0; s < 6; ++s) {
      float A = h7[y0 * 7 + s], B = h7[y0 * 7 + s + 1];
      float C = h7[(y0 + 1) * 7 + s], D = h7[(y0 + 1) * 7 + s + 1];
      for (int xx = segLo[s]; xx < segHi[s]; ++xx) {
        float px = ((float)xx + 0.5f) * (7.f / 224.f) - 0.5f;
        px = fminf(fmaxf(px, 0.f), 6.f);
        float fx = px - (float)s;
        float v = (1.f - fy) * ((1.f - fx) * A + fx * B) +
                  fy * ((1.f - fx) * C + fx * D);
        bool m = v > 0.7f;
        if (m && start < 0) start = xx;
        if (!m && start >= 0) {
          if (n < MAXR) { rx0[yy * MAXR + n] = (short)start; rx1[yy * MAXR + n] = (short)(xx - 1); n++; }
          start = -1;
        }
      }
    }
    if (start >= 0 && n < MAXR) { rx0[yy * MAXR + n] = (short)start; rx1[yy * MAXR + n] = 223; n++; }
    nr[yy] = (short)n;
  }
  __syncthreads();
  int myA0[2], myA1[2];
  bool myV[2];
  #pragma unroll
  for (int j = 0; j < 2; ++j) {
    int i = tid + j * CTH;
    bool v = (i < NRUNS) && ((i & 7) < (int)nr[i >> 3]);
    myV[j] = v;
    myA0[j] = v ? (int)rx0[i] : 0;
    myA1[j] = v ? (int)rx1[i] : 0;
  }
  for (int outer = 0; outer < 128; ++outer) {
    if (tid == 0) chg = 0;
    __syncthreads();
    bool any = false;
    #pragma unroll
    for (int j = 0; j < 2; ++j) {
      if (!myV[j]) continue;
      int i = tid + j * CTH;
      int yy = i >> 3;
      int a0 = myA0[j], a1 = myA1[j];
      int ri = lab[i];
      if (yy > 0) {
        int n1 = nr[yy - 1];
        for (int kk = 0; kk < n1; ++kk) {
          int q = ((yy - 1) << 3) + kk;
          if (a0 <= rx1[q] + 1 && a1 >= rx0[q] - 1) {
            int rq = lab[q];
            if (rq < ri) { atomicMin(&lab[ri], rq); any = true; }
            else if (ri < rq) { atomicMin(&lab[rq], ri); any = true; }
          }
        }
      }
      if (yy < 223) {
        int n1 = nr[yy + 1];
        for (int kk = 0; kk < n1; ++kk) {
          int q = ((yy + 1) << 3) + kk;
          if (a0 <= rx1[q] + 1 && a1 >= rx0[q] - 1) {
            int rq = lab[q];
            if (rq < ri) { atomicMin(&lab[ri], rq); any = true; }
            else if (ri < rq) { atomicMin(&lab[rq], ri); any = true; }
          }
        }
      }
    }
    if (any) chg = 1;
    #pragma unroll
    for (int sc = 0; sc < 3; ++sc) {
      #pragma unroll
      for (int j = 0; j < 2; ++j) {
        int i = tid + j * CTH;
        if (i < NRUNS) {
          int ll = lab[i];
          int l2 = lab[ll];
          if (l2 < ll) lab[i] = l2;
        }
      }
    }
    __syncthreads();
    if (!chg) break;
  }
  for (int i = tid; i < NRUNS; i += CTH) {
    int yy = i >> 3, k = i & 7;
    if (k >= (int)nr[yy]) continue;
    int r = lab[i];
    int a0 = rx0[i], a1 = rx1[i];
    atomicAdd(&cnt[r], a1 - a0 + 1);
    atomicMax(&mid[r], yy * 224 + a1 + 1);
    atomicMin(&rmn[r], yy);
    atomicMax(&rmx[r], yy);
    atomicMin(&cmn[r], a0);
    atomicMax(&cmx[r], a1);
  }
  __syncthreads();
  int bc = -1, bm = 0x7fffffff, bi = -1;
  for (int i = tid; i < NRUNS; i += CTH) {
    if (cnt[i] > 0 && lab[i] == i) {
      if (cnt[i] > bc || (cnt[i] == bc && mid[i] < bm)) { bc = cnt[i]; bm = mid[i]; bi = i; }
    }
  }
  bestC[tid] = bc; bestM[tid] = bm; bestI[tid] = bi;
  __syncthreads();
  for (int st = CTH / 2; st > 0; st >>= 1) {
    if (tid < st) {
      if (bestC[tid + st] > bestC[tid] ||
          (bestC[tid + st] == bestC[tid] && bestM[tid + st] < bestM[tid])) {
        bestC[tid] = bestC[tid + st]; bestM[tid] = bestM[tid + st]; bestI[tid] = bestI[tid + st];
      }
    }
    __syncthreads();
  }
  if (tid == 0) {
    int bw = bestI[0];
    float fy0, chf, fx0, cwf;
    if (bw < 0) { fy0 = 224.f; chf = 1.f; fx0 = 224.f; cwf = 1.f; }
    else {
      int dr = rmx[bw] - rmn[bw]; if (dr < 1) dr = 1;
      int dc = cmx[bw] - cmn[bw]; if (dc < 1) dc = 1;
      fy0 = (float)rmn[bw]; chf = (float)dr;
      fx0 = (float)cmn[bw]; cwf = (float)dc;
    }
    bbox[b * 4 + 0] = fy0; bbox[b * 4 + 1] = chf;
    bbox[b * 4 + 2] = fx0; bbox[b * 4 + 3] = cwf;
  }
}

// ---------------- bilinear crop-resize back to 224x224 ----------------
__global__ __launch_bounds__(256) void k_sample(const float* __restrict__ img,
                                                const float* __restrict__ bbox,
                                                float* __restrict__ patch_out) {
  int idx = blockIdx.x * 256 + threadIdx.x;
  if (idx >= 4 * 3 * 224 * 224) return;
  int b = idx / (3 * 224 * 224);
  int r = idx % (3 * 224 * 224);
  int c = r / (224 * 224);
  int p = r % (224 * 224);
  int oy = p / 224, ox = p % 224;
  float fy0 = bbox[b * 4 + 0], chf = bbox[b * 4 + 1];
  float fx0 = bbox[b * 4 + 2], cwf = bbox[b * 4 + 3];
  float gy = ((float)oy + 0.5f) * (chf / 224.f) + fy0 - 0.5f;
  float gx = ((float)ox + 0.5f) * (cwf / 224.f) + fx0 - 0.5f;
  gy = fminf(fmaxf(gy, fy0), fmaxf(fy0 + chf - 1.f, fy0));
  gx = fminf(fmaxf(gx, fx0), fmaxf(fx0 + cwf - 1.f, fx0));
  int y0 = (int)floorf(gy);
  int x0 = (int)floorf(gx);
  float fy = gy - (float)y0, fx = gx - (float)x0;
  int y0c = min(max(y0, 0), 223), y1c = min(max(y0 + 1, 0), 223);
  int x0c = min(max(x0, 0), 223), x1c = min(max(x0 + 1, 0), 223);
  const float* ip = img + ((size_t)b * 3 + c) * 224 * 224;
  float v00 = ip[y0c * 224 + x0c], v01 = ip[y0c * 224 + x1c];
  float v10 = ip[y1c * 224 + x0c], v11 = ip[y1c * 224 + x1c];
  float v = (1.f - fy) * ((1.f - fx) * v00 + fx * v01) + fy * ((1.f - fx) * v10 + fx * v11);
  patch_out[idx] = v;
}

// ---------------- fallback conv (round-11 proven path) ----------------
template <int CIN, int HIN, int WIN, int COUT, int HOUT, int WOUT, int SPLIT>
__global__ __launch_bounds__(256) void k_convm(const float* __restrict__ x,
                                               const float* __restrict__ wsrc,
                                               float* __restrict__ part) {
  constexpr int NPX = 4 * HOUT * WOUT;
  constexpr int KTOT = (CIN * 9) / SPLIT;
  constexpr int NCH = KTOT / 64;
  __shared__ __align__(16) unsigned short Xs[2][64][64];
  __shared__ __align__(16) unsigned short Wsh[3][64][64];
  __shared__ int pb[64], pyA[64], pxA[64];
  const int tid = threadIdx.x;
  const int oc0 = blockIdx.y * 64, px0 = blockIdx.x * 64;
  const int spl = blockIdx.z;
  const int kg0 = spl * KTOT;
  if (tid < 64) {
    int p = px0 + tid;
    if (p > NPX - 1) p = NPX - 1;
    int hw = HOUT * WOUT;
    pb[tid] = p / hw;
    int r = p % hw;
    pyA[tid] = r / WOUT;
    pxA[tid] = r % WOUT;
  }
  f32x4 acc[4] = {};
  const int l = tid & 63, wv = tid >> 6;
  const int lr = l & 15, lh = l >> 4;
  __syncthreads();
  for (int ch = 0; ch < NCH; ++ch) {
    const int kbase = kg0 + ch * 64;
    #pragma unroll
    for (int j = 0; j < 2; ++j) {
      int c = tid + 256 * j;
      int oc = c >> 3, koct = c & 7;
      const float* wp = wsrc + (size_t)(oc0 + oc) * (CIN * 9) + kbase + koct * 8;
      float vv[8];
      *(float4*)&vv[0] = *(const float4*)wp;
      *(float4*)&vv[4] = *(const float4*)(wp + 4);
      short8m ph, pm, pl2;
      #pragma unroll
      for (int i = 0; i < 8; ++i) {
        unsigned short hb = bf16_trunc(vv[i]);
        float r = vv[i] - bf16_tof(hb);
        unsigned short mb = bf16_rte(r);
        float r2 = r - bf16_tof(mb);
        unsigned short lb = bf16_rte(r2);
        ph[i] = (short)hb; pm[i] = (short)mb; pl2[i] = (short)lb;
      }
      *ldsPtr(&Wsh[0][0][0], oc, koct * 16) = ph;
      *ldsPtr(&Wsh[1][0][0], oc, koct * 16) = pm;
      *ldsPtr(&Wsh[2][0][0], oc, koct * 16) = pl2;
    }
    #pragma unroll
    for (int j = 0; j < 2; ++j) {
      int c = tid + 256 * j;
      int px = c & 63, koct = c >> 6;
      int pbv = pb[px], py = pyA[px], pxv = pxA[px];
      float vv[8];
      #pragma unroll
      for (int i = 0; i < 8; ++i) {
        int k = kbase + koct * 8 + i;
        int ci = k / 9, tap = k - ci * 9;
        int iy = py * 2 - 1 + tap / 3, ix = pxv * 2 - 1 + (tap % 3);
        float v = 0.f;
        if ((unsigned)iy < (unsigned)HIN && (unsigned)ix < (unsigned)WIN)
          v = x[(((size_t)pbv * CIN + ci) * HIN + iy) * WIN + ix];
        vv[i] = v;
      }
      short8m ph, pm;
      #pragma unroll
      for (int i = 0; i < 8; ++i) {
        unsigned short hb = bf16_trunc(vv[i]);
        unsigned short mb = bf16_rte(vv[i] - bf16_tof(hb));
        ph[i] = (short)hb; pm[i] = (short)mb;
      }
      *ldsPtr(&Xs[0][0][0], px, koct * 16) = ph;
      *ldsPtr(&Xs[1][0][0], px, koct * 16) = pm;
    }
    __syncthreads();
    #pragma unroll
    for (int ks = 0; ks < 2; ++ks) {
      const int kbyte = ks * 64 + lh * 16;
      short8m aH = *ldsPtr(&Wsh[0][0][0], wv * 16 + lr, kbyte);
      short8m aM = *ldsPtr(&Wsh[1][0][0], wv * 16 + lr, kbyte);
      short8m aL = *ldsPtr(&Wsh[2][0][0], wv * 16 + lr, kbyte);
      #pragma unroll
      for (int g = 0; g < 4; ++g) {
        short8m bH = *ldsPtr(&Xs[0][0][0], g * 16 + lr, kbyte);
        short8m bM = *ldsPtr(&Xs[1][0][0], g * 16 + lr, kbyte);
        acc[g] = __builtin_amdgcn_mfma_f32_16x16x32_bf16(aH, bH, acc[g], 0, 0, 0);
        acc[g] = __builtin_amdgcn_mfma_f32_16x16x32_bf16(aH, bM, acc[g], 0, 0, 0);
        acc[g] = __builtin_amdgcn_mfma_f32_16x16x32_bf16(aM, bH, acc[g], 0, 0, 0);
        acc[g] = __builtin_amdgcn_mfma_f32_16x16x32_bf16(aM, bM, acc[g], 0, 0, 0);
        acc[g] = __builtin_amdgcn_mfma_f32_16x16x32_bf16(aL, bH, acc[g], 0, 0, 0);
      }
    }
    __syncthreads();
  }
  const size_t N = (size_t)4 * COUT * HOUT * WOUT;
  #pragma unroll
  for (int g = 0; g < 4; ++g) {
    int pxl = g * 16 + lr;
    int pidx = px0 + pxl;
    if (pidx < NPX) {
      #pragma unroll
      for (int r = 0; r < 4; ++r) {
        int ocl = wv * 16 + lh * 4 + r;
        part[(size_t)spl * N +
             (((size_t)pb[pxl] * COUT + (oc0 + ocl)) * HOUT + pyA[pxl]) * WOUT + pxA[pxl]] =
            acc[g][r];
      }
    }
  }
}

extern "C" void kernel_launch(void* const* d_in, const int* in_sizes, int n_in,
                              void* d_out, int out_size, void* d_ws, size_t ws_size,
                              hipStream_t stream) {
  const float* img = (const float*)d_in[0];
  const float* target = (const float*)d_in[1];
  const float* gw0 = (const float*)d_in[2];
  const float* gw1 = (const float*)d_in[3];
  const float* gw2 = (const float*)d_in[4];
  const float* gw3 = (const float*)d_in[5];
  const float* gfw = (const float*)d_in[6];
  const float* gfb = (const float*)d_in[7];
  const float* lw0 = (const float*)d_in[8];
  const float* lw1 = (const float*)d_in[9];
  const float* lw2 = (const float*)d_in[10];
  const float* lw3 = (const float*)d_in[11];
  const float* lfw = (const float*)d_in[12];
  const float* lfb = (const float*)d_in[13];
  const float* fw = (const float*)d_in[14];
  const float* fb = (const float*)d_in[15];
  float* out = (float*)d_out;
  float* ws = (float*)d_ws;

  float* c1 = ws;                    // 802816   [4,64,56,56]
  float* c2 = c1 + 802816;           // 1605632  [4,512,28,28]
  float* c3 = c2 + 1605632;          // 802816   [4,1024,14,14]
  float* c4 = c3 + 802816;           // 401408   [4,2048,7,7]
  float* poolg = c4 + 401408;        // 8192
  float* pooll = poolg + 8192;       // 8192
  float* hm7 = pooll + 8192;         // 196
  float* hmr = hm7 + 196;            // 196
  float* bbox = hmr + 196;           // 16
  float* patch = ws + 3629568;       // 602112 (fallback path only)

  // TIER1 layout (r23): part 3.2M floats @4231680, Xg @7442944 (3.84M ushorts/plane)
  float* part1 = ws + 4231680;
  float* Wp1 = part1 + 2800000;
  unsigned short* XgH1 = (unsigned short*)(ws + 7442944);
  unsigned short* XgM1 = XgH1 + 3840000;
  // TIER2 layout: part @4231680 (<=3.3M floats used), Xg @10654208 (4.2M ushorts/plane)
  float* part2 = ws + 4231680;
  unsigned short* XgH2 = (unsigned short*)(ws + 10654208);
  unsigned short* XgM2 = XgH2 + 4200448;

  const bool tier2 = ws_size >= (size_t)59419648;
  const bool fast = ws_size >= (size_t)45131776;

  dim3 g7(13, 256);
  const int rg2 = 2048, rg3 = 2048, rg4 = 1568;

  for (int pass = 0; pass < 2; ++pass) {
    const float* w0 = pass ? lw0 : gw0;
    const float* w1 = pass ? lw1 : gw1;
    const float* w2 = pass ? lw2 : gw2;
    const float* w3 = pass ? lw3 : gw3;
    const float* fwp = pass ? lfw : gfw;
    const float* fbp = pass ? lfb : gfb;
    const float* inp = pass ? (fast ? (out + 169) : patch) : img;
    float* pool = pass ? pooll : poolg;
    float* outp = pass ? (out + 57) : (out + 1);

    if (tier2) {
      float* part = part2;
      unsigned short* XgH = XgH2;
      unsigned short* XgM = XgM2;
      float* Wp = part2;   // conv7-time only; part region free then
      k_padw<<<48, 256, 0, stream>>>(w0, Wp, 147, 192, 64);
      k_im2col<3, 224, 224, 56, 56, 7, 7, 4, 3, 192, 64><<<1176, 256, 0, stream>>>(inp, XgH, XgM);
      k_gemm<64, 56, 56, 192, 1, 64, 64><<<196, 256, 0, stream>>>(XgH, XgM, Wp, c1);
      k_im2col<64, 56, 56, 28, 28, 3, 3, 2, 1, 576, 64><<<882, 256, 0, stream>>>(c1, XgH, XgM);
      k_gemm<512, 28, 28, 576, 1, 128, 64><<<196, 512, 0, stream>>>(XgH, XgM, w1, c2);
      k_im2col<512, 28, 28, 14, 14, 3, 3, 2, 1, 4608, 128><<<2016, 256, 0, stream>>>(c2, XgH, XgM);
      k_gemm<1024, 14, 14, 4608, 4, 128, 128><<<224, 512, 0, stream>>>(XgH, XgM, w2, part);
      k_red<4><<<rg3, 256, 0, stream>>>(part, c3, 802816);
      k_im2col<1024, 14, 14, 7, 7, 3, 3, 2, 1, 9216, 128><<<1152, 256, 0, stream>>>(c3, XgH, XgM);
      k_gemm<2048, 7, 7, 9216, 8, 128, 128><<<256, 512, 0, stream>>>(XgH, XgM, w3, part);
      k_red<8><<<rg4, 256, 0, stream>>>(part, c4, 401408);
    } else if (fast) {
      float* part = part1;
      unsigned short* XgH = XgH1;
      unsigned short* XgM = XgM1;
      float* Wp = Wp1;
      k_padw<<<48, 256, 0, stream>>>(w0, Wp, 147, 192, 64);
      k_im2col<3, 224, 224, 56, 56, 7, 7, 4, 3, 192, 64><<<1176, 256, 0, stream>>>(inp, XgH, XgM);
      k_gemm<64, 56, 56, 192, 1, 64, 64><<<196, 256, 0, stream>>>(XgH, XgM, Wp, c1);
      k_im2col<64, 56, 56, 28, 28, 3, 3, 2, 1, 576, 64><<<882, 256, 0, stream>>>(c1, XgH, XgM);
      k_gemm<512, 28, 28, 576, 1, 128, 64><<<196, 512, 0, stream>>>(XgH, XgM, w1, c2);
      k_im2col<512, 28, 28, 14, 14, 3, 3, 2, 1, 4608, 64><<<1872, 256, 0, stream>>>(c2, XgH, XgM);
      k_gemm<1024, 14, 14, 4608, 4, 128, 64><<<416, 512, 0, stream>>>(XgH, XgM, w2, part);
      k_red<4><<<rg3, 256, 0, stream>>>(part, c3, 802816);
      k_im2col<1024, 14, 14, 7, 7, 3, 3, 2, 1, 9216, 64><<<1152, 256, 0, stream>>>(c3, XgH, XgM);
      k_gemm<2048, 7, 7, 9216, 8, 128, 64><<<512, 512, 0, stream>>>(XgH, XgM, w3, part);
      k_red<8><<<rg4, 256, 0, stream>>>(part, c4, 401408);
    } else {
      float* part = part1;
      k_conv7<<<g7, 256, 0, stream>>>(inp, w0, c1);
      k_convm<64, 56, 56, 512, 28, 28, 1><<<dim3(49, 8, 1), 256, 0, stream>>>(c1, w1, part);
      k_red<1><<<rg2, 256, 0, stream>>>(part, c2, 1605632);
      k_convm<512, 28, 28, 1024, 14, 14, 4><<<dim3(13, 16, 4), 256, 0, stream>>>(c2, w2, part);
      k_red<4><<<rg3, 256, 0, stream>>>(part, c3, 802816);
      k_convm<1024, 14, 14, 2048, 7, 7, 8><<<dim3(4, 32, 8), 256, 0, stream>>>(c3, w3, part);
      k_red<8><<<rg4, 256, 0, stream>>>(part, c4, 401408);
    }
    k_pool<<<32, 256, 0, stream>>>(c4, pool);
    k_fcsig<<<56, 256, 0, stream>>>(pool, fwp, fbp, outp);

    if (pass == 0) {
      k_hm7a<<<196, 256, 0, stream>>>(c4, hmr);
      k_hm7b<<<4, 64, 0, stream>>>(hmr, hm7);
      k_ccl<<<4, CTH, 0, stream>>>(hm7, bbox);
      k_sample<<<2352, 256, 0, stream>>>(img, bbox, out + 169);
      if (!fast) k_sample<<<2352, 256, 0, stream>>>(img, bbox, patch);
    }
  }
  // fusion FC (parallel) + loss (tiny)
  k_fcsig2<<<56, 256, 0, stream>>>(poolg, pooll, fw, fb, out + 113);
  k_loss<<<1, 64, 0, stream>>>(target, out);
}

// Round 26
// 328.096 us; speedup vs baseline: 1.1060x; 1.1060x over previous
//
#include <hip/hip_runtime.h>
#include <math.h>

typedef __attribute__((ext_vector_type(8))) short short8m;   // 8 bf16 (4 VGPRs)
typedef __attribute__((ext_vector_type(4))) float f32x4;

__device__ inline unsigned short bf16_trunc(float f) {
  return (unsigned short)(__float_as_uint(f) >> 16);
}
__device__ inline unsigned short bf16_rte(float f) {
  unsigned u = __float_as_uint(f);
  u += 0x7fffu + ((u >> 16) & 1u);
  return (unsigned short)(u >> 16);
}
__device__ inline float bf16_tof(unsigned short h) {
  return __uint_as_float(((unsigned)h) << 16);
}
// LDS XOR-swizzle for W tiles: row pitch 128B; byte ^= ((row&7)<<4) -> conflict-free b128 r/w
__device__ inline short8m* ldsPtr(unsigned short* base, int row, int byteInRow) {
  int off = (row * 128 + byteInRow) ^ ((row & 7) << 4);
  return (short8m*)((char*)base + off);
}
__device__ inline void gload16_lds(const void* g, void* d) {
  __builtin_amdgcn_global_load_lds((const __attribute__((address_space(1))) unsigned int*)g,
                                   (__attribute__((address_space(3))) unsigned int*)d, 16, 0, 0);
}

// ---------------- conv 7x7 direct (fallback path only) ----------------
__global__ __launch_bounds__(256) void k_conv7(const float* __restrict__ x,
                                               const float* __restrict__ w,
                                               float* __restrict__ y) {
  __shared__ float ws[147];
  const int boc = blockIdx.y;
  const int oc = boc & 63;
  const int b = boc >> 6;
  for (int i = threadIdx.x; i < 147; i += 256) ws[i] = w[oc * 147 + i];
  __syncthreads();
  int px = blockIdx.x * 256 + threadIdx.x;
  if (px >= 56 * 56) return;
  int oy = px / 56, ox = px % 56;
  int iy0 = oy * 4 - 3, ix0 = ox * 4 - 3;
  float acc = 0.f;
  for (int c = 0; c < 3; ++c) {
    const float* xp = x + ((size_t)(b * 3 + c)) * 224 * 224;
    #pragma unroll
    for (int ky = 0; ky < 7; ++ky) {
      int iy = iy0 + ky;
      if ((unsigned)iy < 224u) {
        #pragma unroll
        for (int kx = 0; kx < 7; ++kx) {
          int ix = ix0 + kx;
          if ((unsigned)ix < 224u)
            acc += xp[iy * 224 + ix] * ws[c * 49 + ky * 7 + kx];
        }
      }
    }
  }
  y[((size_t)boc * 56 + oy) * 56 + ox] = fmaxf(acc, 0.f);
}

// ---------------- zero-pad weights along K ----------------
__global__ __launch_bounds__(256) void k_padw(const float* __restrict__ w,
                                              float* __restrict__ wp,
                                              int kreal, int ktot, int noc) {
  int i = blockIdx.x * 256 + threadIdx.x;
  if (i >= noc * ktot) return;
  int oc = i / ktot, k = i % ktot;
  wp[i] = (k < kreal) ? w[oc * kreal + k] : 0.f;
}

// ---------------- generic im2col + 2-plane bf16 split, block-tiled (PXT px per tile) ----
template <int CIN, int HIN, int WIN, int HOUT, int WOUT, int KH, int KW, int STR, int PAD,
          int KTOT, int PXT>
__global__ __launch_bounds__(256) void k_im2col(const float* __restrict__ x,
                                                unsigned short* __restrict__ XgH,
                                                unsigned short* __restrict__ XgM) {
  constexpr int NPX = 4 * HOUT * WOUT;
  constexpr int K8 = KTOT / 8;
  constexpr int KK = KH * KW;
  int u = blockIdx.x * 256 + threadIdx.x;
  int pxin = u % PXT;
  int rest = u / PXT;
  int k8 = rest % K8;
  int pxblk = rest / K8;
  int px = pxblk * PXT + pxin;
  if (px > NPX - 1) px = NPX - 1;          // pad replication
  const int hw = HOUT * WOUT;
  int pbv = px / hw;
  int r = px % hw;
  int py = r / WOUT, pxv = r % WOUT;
  short8m ph, pm;
  #pragma unroll
  for (int i = 0; i < 8; ++i) {
    int k = k8 * 8 + i;
    int ci = k / KK, tap = k - ci * KK;
    float v = 0.f;
    if (ci < CIN) {
      int iy = py * STR - PAD + tap / KW, ix = pxv * STR - PAD + (tap % KW);
      if ((unsigned)iy < (unsigned)HIN && (unsigned)ix < (unsigned)WIN)
        v = x[(((size_t)pbv * CIN + ci) * HIN + iy) * WIN + ix];
    }
    unsigned short hb = bf16_trunc(v);
    unsigned short mb = bf16_rte(v - bf16_tof(hb));
    ph[i] = (short)hb; pm[i] = (short)mb;
  }
  size_t off = (size_t)u * 8;
  *(short8m*)(XgH + off) = ph;
  *(short8m*)(XgM + off) = pm;
}

// ---------------- GEMM (r20-proven structure; OCT x PXT tile) ----------------
template <int COUT, int HOUT, int WOUT, int KTOT, int SPLIT, int OCT, int PXT>
__global__ __launch_bounds__(OCT * 4) void k_gemm(const unsigned short* __restrict__ XgH,
                                                  const unsigned short* __restrict__ XgM,
                                                  const float* __restrict__ wsrc,
                                                  float* __restrict__ part) {
  constexpr int NPX = 4 * HOUT * WOUT;
  constexpr int NPXB = (NPX + PXT - 1) / PXT;
  constexpr int NOCB = COUT / OCT;
  constexpr int NWG = NPXB * NOCB * SPLIT;
  constexpr int KCH = KTOT / SPLIT;
  constexpr int NCH = KCH / 64;
  constexpr int NTHR = OCT * 4;
  constexpr int NWAVE = NTHR / 64;
  constexpr int NG = PXT / 16;          // px groups per wave
  constexpr int SPP = PXT / 64;         // 64-lane slabs per koct per plane
  constexpr int TS = 16 * SPP;          // total slabs (both planes)
  constexpr int SLABSW = TS / NWAVE;    // slabs per wave
  __shared__ __align__(16) unsigned short XsH[PXT * 64];   // [8 koct][PXT px][8 k]
  __shared__ __align__(16) unsigned short XsM[PXT * 64];
  __shared__ __align__(16) unsigned short WsH[OCT * 64];   // swizzled [OCT oc][64 k]
  __shared__ __align__(16) unsigned short WsM[OCT * 64];
  __shared__ int pb[PXT], pyA[PXT], pxA[PXT];
  const int tid = threadIdx.x;
  const int flat = blockIdx.x;
  constexpr int q = NWG >> 3, r = NWG & 7;
  const int xc = flat & 7, of = flat >> 3;
  const int work = ((xc < r) ? xc * (q + 1) : r * (q + 1) + (xc - r) * q) + of;
  const int pxblk = work % NPXB;
  const int t2 = work / NPXB;
  const int oc0 = (t2 % NOCB) * OCT;
  const int spl = t2 / NOCB;
  if (tid < PXT) {
    int p = pxblk * PXT + tid;
    if (p > NPX - 1) p = NPX - 1;
    int hw = HOUT * WOUT;
    pb[tid] = p / hw;
    int rr = p % hw;
    pyA[tid] = rr / WOUT;
    pxA[tid] = rr % WOUT;
  }
  f32x4 acc[NG] = {};
  const int l = tid & 63, wv = tid >> 6;
  const int lr = l & 15, lh = l >> 4;
  __syncthreads();
  for (int ch = 0; ch < NCH; ++ch) {
    const int kbase = spl * KCH + ch * 64;
    const size_t tileOff = (size_t)pxblk * KTOT * PXT + (size_t)kbase * PXT;
    #pragma unroll
    for (int t = 0; t < SLABSW; ++t) {
      int ins = wv * SLABSW + t;
      int pl = ins >= (TS / 2);
      int wp = ins - pl * (TS / 2);
      int ko = wp / SPP, sp = wp % SPP;
      const unsigned short* g =
          (pl ? XgM : XgH) + tileOff + (size_t)ko * (PXT * 8) + sp * 512 + l * 8;
      unsigned short* d = (pl ? XsM : XsH) + ko * (PXT * 8) + sp * 512;
      gload16_lds(g, d);
    }
    #pragma unroll
    for (int j = 0; j < 2; ++j) {
      int c = tid + NTHR * j;
      int oc = c >> 3, koct = c & 7;
      const float* wp = wsrc + (size_t)(oc0 + oc) * KTOT + kbase + koct * 8;
      float vv[8];
      *(float4*)&vv[0] = *(const float4*)wp;
      *(float4*)&vv[4] = *(const float4*)(wp + 4);
      short8m ph, pm;
      #pragma unroll
      for (int i = 0; i < 8; ++i) {
        unsigned short hb = bf16_trunc(vv[i]);
        unsigned short mb = bf16_rte(vv[i] - bf16_tof(hb));
        ph[i] = (short)hb; pm[i] = (short)mb;
      }
      *ldsPtr(WsH, oc, koct * 16) = ph;
      *ldsPtr(WsM, oc, koct * 16) = pm;
    }
    __syncthreads();                       // drains vmcnt (global_load_lds) + lgkm
    #pragma unroll
    for (int ks = 0; ks < 2; ++ks) {
      const int kbyte = ks * 64 + lh * 16;
      short8m aH = *ldsPtr(WsH, wv * 16 + lr, kbyte);
      short8m aM = *ldsPtr(WsM, wv * 16 + lr, kbyte);
      const int xoff = (ks * 4 + lh) * (PXT * 8);
      #pragma unroll
      for (int g4 = 0; g4 < NG; ++g4) {
        short8m bH = *(const short8m*)(XsH + xoff + (g4 * 16 + lr) * 8);
        short8m bM = *(const short8m*)(XsM + xoff + (g4 * 16 + lr) * 8);
        acc[g4] = __builtin_amdgcn_mfma_f32_16x16x32_bf16(aH, bH, acc[g4], 0, 0, 0);
        acc[g4] = __builtin_amdgcn_mfma_f32_16x16x32_bf16(aH, bM, acc[g4], 0, 0, 0);
        acc[g4] = __builtin_amdgcn_mfma_f32_16x16x32_bf16(aM, bH, acc[g4], 0, 0, 0);
      }
    }
    __syncthreads();
  }
  const size_t N = (size_t)4 * COUT * HOUT * WOUT;
  #pragma unroll
  for (int g4 = 0; g4 < NG; ++g4) {
    int pxl = g4 * 16 + lr;
    int pidx = pxblk * PXT + pxl;
    if (pidx < NPX) {
      #pragma unroll
      for (int rr = 0; rr < 4; ++rr) {
        int ocl = wv * 16 + lh * 4 + rr;
        float v = acc[g4][rr];
        if (SPLIT == 1) v = fmaxf(v, 0.f);   // fused ReLU (direct output)
        part[(size_t)spl * N +
             (((size_t)pb[pxl] * COUT + (oc0 + ocl)) * HOUT + pyA[pxl]) * WOUT + pxA[pxl]] = v;
      }
    }
  }
}

// ---------------- split-K reduction + ReLU ----------------
template <int SPLIT>
__global__ __launch_bounds__(256) void k_red(const float* __restrict__ part,
                                             float* __restrict__ y, int n) {
  for (int i = blockIdx.x * 256 + threadIdx.x; i < n; i += gridDim.x * 256) {
    float s = 0.f;
    #pragma unroll
    for (int sp = 0; sp < SPLIT; ++sp) s += part[(size_t)sp * n + i];
    y[i] = fmaxf(s, 0.f);
  }
}

// ---------------- global-max-pool (7x7): one thread per (b,ch) ----------------
__global__ __launch_bounds__(256) void k_pool(const float* __restrict__ feat,
                                              float* __restrict__ pool) {
  int idx = blockIdx.x * 256 + threadIdx.x;
  if (idx >= 8192) return;
  const float* fp = feat + (size_t)idx * 49;
  float m = fp[0];
  #pragma unroll
  for (int i = 1; i < 49; ++i) m = fmaxf(m, fp[i]);
  pool[idx] = m;
}

// ---------------- FC(2048->14) + sigmoid: one block per (b,c) ----------------
__global__ __launch_bounds__(256) void k_fcsig(const float* __restrict__ pool,
                                               const float* __restrict__ fw,
                                               const float* __restrict__ fb,
                                               float* __restrict__ outp) {
  __shared__ float red[256];
  const int blk = blockIdx.x;       // b*14 + c
  const int b = blk / 14, c = blk % 14;
  const int tid = threadIdx.x;
  float s = 0.f;
  for (int k = tid; k < 2048; k += 256) s += pool[b * 2048 + k] * fw[c * 2048 + k];
  red[tid] = s;
  __syncthreads();
  for (int st = 128; st > 0; st >>= 1) {
    if (tid < st) red[tid] += red[tid + st];
    __syncthreads();
  }
  if (tid == 0) outp[b * 14 + c] = 1.f / (1.f + expf(-(red[0] + fb[c])));
}

// ---------------- fused FC(4096->14) + sigmoid for out_f ----------------
__global__ __launch_bounds__(256) void k_fcsig2(const float* __restrict__ poolg,
                                                const float* __restrict__ pooll,
                                                const float* __restrict__ fw,
                                                const float* __restrict__ fb,
                                                float* __restrict__ outp) {
  __shared__ float red[256];
  const int blk = blockIdx.x;       // b*14 + c
  const int b = blk / 14, c = blk % 14;
  const int tid = threadIdx.x;
  const float* w = fw + (size_t)c * 4096;
  float s = 0.f;
  for (int k = tid; k < 2048; k += 256) s += poolg[b * 2048 + k] * w[k];
  for (int k = tid; k < 2048; k += 256) s += pooll[b * 2048 + k] * w[2048 + k];
  red[tid] = s;
  __syncthreads();
  for (int st = 128; st > 0; st >>= 1) {
    if (tid < st) red[tid] += red[tid + st];
    __syncthreads();
  }
  if (tid == 0) outp[blk] = 1.f / (1.f + expf(-(red[0] + fb[c])));
}

// ---------------- loss: weighted BCEs ----------------
__global__ __launch_bounds__(64) void k_loss(const float* __restrict__ target,
                                             float* __restrict__ dout) {
  __shared__ float red[64];
  const int tid = threadIdx.x;
  float term = 0.f;
  if (tid < 56) {
    float t = target[tid];
    float pg = dout[1 + tid], plo = dout[57 + tid], pf = dout[113 + tid];
    auto bce1 = [&](float pp) {
      pp = fminf(fmaxf(pp, 1e-7f), 1.f - 1e-7f);
      return -(t * logf(pp) + (1.f - t) * log1pf(-pp));
    };
    term = (0.8f * bce1(pg) + 0.1f * bce1(plo) + 0.1f * bce1(pf)) * (1.f / 56.f);
  }
  red[tid] = term;
  __syncthreads();
  for (int st = 32; st > 0; st >>= 1) {
    if (tid < st) red[tid] += red[tid + st];
    __syncthreads();
  }
  if (tid == 0) dout[0] = red[0];
}

// ---------------- heatmap stage A: per-(b,cell) channel max|.| ----------------
__global__ __launch_bounds__(256) void k_hm7a(const float* __restrict__ feat,
                                              float* __restrict__ hmr) {
  __shared__ float red[256];
  const int b = blockIdx.x / 49, cell = blockIdx.x % 49;
  const int tid = threadIdx.x;
  float m = 0.f;
  for (int ch = tid; ch < 2048; ch += 256)
    m = fmaxf(m, fabsf(feat[((size_t)b * 2048 + ch) * 49 + cell]));
  red[tid] = m;
  __syncthreads();
  for (int st = 128; st > 0; st >>= 1) {
    if (tid < st) red[tid] = fmaxf(red[tid], red[tid + st]);
    __syncthreads();
  }
  if (tid == 0) hmr[b * 49 + cell] = red[0];
}

// ---------------- heatmap stage B: per-sample min-max normalize ----------------
__global__ __launch_bounds__(64) void k_hm7b(const float* __restrict__ hmr,
                                             float* __restrict__ hm7) {
  __shared__ float h[49];
  const int b = blockIdx.x, tid = threadIdx.x;
  if (tid < 49) h[tid] = hmr[b * 49 + tid];
  __syncthreads();
  if (tid == 0) {
    float mn = h[0], mx = h[0];
    for (int i = 1; i < 49; ++i) {
      mn = fminf(mn, h[i]);
      mx = fmaxf(mx, h[i]);
    }
    for (int i = 0; i < 49; ++i) hm7[b * 49 + i] = (h[i] - mn) / (mx - mn);
  }
}

// ---------------- parallel CCL: 1024 threads (16 waves -> 4/SIMD latency hiding) --------
#define MAXR 8
#define NRUNS (224 * MAXR)
#define CTH 1024
__global__ __launch_bounds__(CTH) void k_ccl(const float* __restrict__ hm7, float* __restrict__ bbox) {
  const int b = blockIdx.x, tid = threadIdx.x;
  __shared__ float h7[49];
  __shared__ short rx0[NRUNS], rx1[NRUNS];
  __shared__ short nr[224];
  __shared__ int lab[NRUNS];
  __shared__ int cnt[NRUNS], mid[NRUNS];
  __shared__ int rmn[NRUNS], rmx[NRUNS], cmn[NRUNS], cmx[NRUNS];
  __shared__ int chg;
  __shared__ int bestC[CTH], bestM[CTH], bestI[CTH];

  if (tid < 49) h7[tid] = hm7[b * 49 + tid];
  for (int i = tid; i < NRUNS; i += CTH) {
    cnt[i] = 0; mid[i] = -1;
    rmn[i] = 1 << 30; rmx[i] = -1; cmn[i] = 1 << 30; cmx[i] = -1;
    lab[i] = i;
  }
  __syncthreads();
  if (tid < 224) {
    int yy = tid;
    float py = ((float)yy + 0.5f) * (7.f / 224.f) - 0.5f;
    py = fminf(fmaxf(py, 0.f), 6.f);
    int y0 = (int)floorf(py);
    if (y0 > 5) y0 = 5;
    float fy = py - (float)y0;
    int n = 0, start = -1;
    const int segLo[6] = {0, 48, 80, 112, 144, 176};
    const int segHi[6] = {48, 80, 112, 144, 176, 224};
    #pragma unroll
    for (int s = 0; s < 6; ++s) {
      float A = h7[y0 * 7 + s], B = h7[y0 * 7 + s + 1];
      float C = h7[(y0 + 1) * 7 + s], D = h7[(y0 + 1) * 7 + s + 1];
      for (int xx = segLo[s]; xx < segHi[s]; ++xx) {
        float px = ((float)xx + 0.5f) * (7.f / 224.f) - 0.5f;
        px = fminf(fmaxf(px, 0.f), 6.f);
        float fx = px - (float)s;
        float v = (1.f - fy) * ((1.f - fx) * A + fx * B) +
                  fy * ((1.f - fx) * C + fx * D);
        bool m = v > 0.7f;
        if (m && start < 0) start = xx;
        if (!m && start >= 0) {
          if (n < MAXR) { rx0[yy * MAXR + n] = (short)start; rx1[yy * MAXR + n] = (short)(xx - 1); n++; }
          start = -1;
        }
      }
    }
    if (start >= 0 && n < MAXR) { rx0[yy * MAXR + n] = (short)start; rx1[yy * MAXR + n] = 223; n++; }
    nr[yy] = (short)n;
  }
  __syncthreads();
  int myA0[2], myA1[2];
  bool myV[2];
  #pragma unroll
  for (int j = 0; j < 2; ++j) {
    int i = tid + j * CTH;
    bool v = (i < NRUNS) && ((i & 7) < (int)nr[i >> 3]);
    myV[j] = v;
    myA0[j] = v ? (int)rx0[i] : 0;
    myA1[j] = v ? (int)rx1[i] : 0;
  }
  for (int outer = 0; outer < 128; ++outer) {
    if (tid == 0) chg = 0;
    __syncthreads();
    bool any = false;
    #pragma unroll
    for (int j = 0; j < 2; ++j) {
      if (!myV[j]) continue;
      int i = tid + j * CTH;
      int yy = i >> 3;
      int a0 = myA0[j], a1 = myA1[j];
      int ri = lab[i];
      if (yy > 0) {
        int n1 = nr[yy - 1];
        for (int kk = 0; kk < n1; ++kk) {
          int q = ((yy - 1) << 3) + kk;
          if (a0 <= rx1[q] + 1 && a1 >= rx0[q] - 1) {
            int rq = lab[q];
            if (rq < ri) { atomicMin(&lab[ri], rq); any = true; }
            else if (ri < rq) { atomicMin(&lab[rq], ri); any = true; }
          }
        }
      }
      if (yy < 223) {
        int n1 = nr[yy + 1];
        for (int kk = 0; kk < n1; ++kk) {
          int q = ((yy + 1) << 3) + kk;
          if (a0 <= rx1[q] + 1 && a1 >= rx0[q] - 1) {
            int rq = lab[q];
            if (rq < ri) { atomicMin(&lab[ri], rq); any = true; }
            else if (ri < rq) { atomicMin(&lab[rq], ri); any = true; }
          }
        }
      }
    }
    if (any) chg = 1;
    #pragma unroll
    for (int sc = 0; sc < 3; ++sc) {
      #pragma unroll
      for (int j = 0; j < 2; ++j) {
        int i = tid + j * CTH;
        if (i < NRUNS) {
          int ll = lab[i];
          int l2 = lab[ll];
          if (l2 < ll) lab[i] = l2;
        }
      }
    }
    __syncthreads();
    if (!chg) break;
  }
  for (int i = tid; i < NRUNS; i += CTH) {
    int yy = i >> 3, k = i & 7;
    if (k >= (int)nr[yy]) continue;
    int r = lab[i];
    int a0 = rx0[i], a1 = rx1[i];
    atomicAdd(&cnt[r], a1 - a0 + 1);
    atomicMax(&mid[r], yy * 224 + a1 + 1);
    atomicMin(&rmn[r], yy);
    atomicMax(&rmx[r], yy);
    atomicMin(&cmn[r], a0);
    atomicMax(&cmx[r], a1);
  }
  __syncthreads();
  int bc = -1, bm = 0x7fffffff, bi = -1;
  for (int i = tid; i < NRUNS; i += CTH) {
    if (cnt[i] > 0 && lab[i] == i) {
      if (cnt[i] > bc || (cnt[i] == bc && mid[i] < bm)) { bc = cnt[i]; bm = mid[i]; bi = i; }
    }
  }
  bestC[tid] = bc; bestM[tid] = bm; bestI[tid] = bi;
  __syncthreads();
  for (int st = CTH / 2; st > 0; st >>= 1) {
    if (tid < st) {
      if (bestC[tid + st] > bestC[tid] ||
          (bestC[tid + st] == bestC[tid] && bestM[tid + st] < bestM[tid])) {
        bestC[tid] = bestC[tid + st]; bestM[tid] = bestM[tid + st]; bestI[tid] = bestI[tid + st];
      }
    }
    __syncthreads();
  }
  if (tid == 0) {
    int bw = bestI[0];
    float fy0, chf, fx0, cwf;
    if (bw < 0) { fy0 = 224.f; chf = 1.f; fx0 = 224.f; cwf = 1.f; }
    else {
      int dr = rmx[bw] - rmn[bw]; if (dr < 1) dr = 1;
      int dc = cmx[bw] - cmn[bw]; if (dc < 1) dc = 1;
      fy0 = (float)rmn[bw]; chf = (float)dr;
      fx0 = (float)cmn[bw]; cwf = (float)dc;
    }
    bbox[b * 4 + 0] = fy0; bbox[b * 4 + 1] = chf;
    bbox[b * 4 + 2] = fx0; bbox[b * 4 + 3] = cwf;
  }
}

// ---------------- bilinear crop-resize back to 224x224 ----------------
__global__ __launch_bounds__(256) void k_sample(const float* __restrict__ img,
                                                const float* __restrict__ bbox,
                                                float* __restrict__ patch_out) {
  int idx = blockIdx.x * 256 + threadIdx.x;
  if (idx >= 4 * 3 * 224 * 224) return;
  int b = idx / (3 * 224 * 224);
  int r = idx % (3 * 224 * 224);
  int c = r / (224 * 224);
  int p = r % (224 * 224);
  int oy = p / 224, ox = p % 224;
  float fy0 = bbox[b * 4 + 0], chf = bbox[b * 4 + 1];
  float fx0 = bbox[b * 4 + 2], cwf = bbox[b * 4 + 3];
  float gy = ((float)oy + 0.5f) * (chf / 224.f) + fy0 - 0.5f;
  float gx = ((float)ox + 0.5f) * (cwf / 224.f) + fx0 - 0.5f;
  gy = fminf(fmaxf(gy, fy0), fmaxf(fy0 + chf - 1.f, fy0));
  gx = fminf(fmaxf(gx, fx0), fmaxf(fx0 + cwf - 1.f, fx0));
  int y0 = (int)floorf(gy);
  int x0 = (int)floorf(gx);
  float fy = gy - (float)y0, fx = gx - (float)x0;
  int y0c = min(max(y0, 0), 223), y1c = min(max(y0 + 1, 0), 223);
  int x0c = min(max(x0, 0), 223), x1c = min(max(x0 + 1, 0), 223);
  const float* ip = img + ((size_t)b * 3 + c) * 224 * 224;
  float v00 = ip[y0c * 224 + x0c], v01 = ip[y0c * 224 + x1c];
  float v10 = ip[y1c * 224 + x0c], v11 = ip[y1c * 224 + x1c];
  float v = (1.f - fy) * ((1.f - fx) * v00 + fx * v01) + fy * ((1.f - fx) * v10 + fx * v11);
  patch_out[idx] = v;
}

// ---------------- fallback conv (round-11 proven path) ----------------
template <int CIN, int HIN, int WIN, int COUT, int HOUT, int WOUT, int SPLIT>
__global__ __launch_bounds__(256) void k_convm(const float* __restrict__ x,
                                               const float* __restrict__ wsrc,
                                               float* __restrict__ part) {
  constexpr int NPX = 4 * HOUT * WOUT;
  constexpr int KTOT = (CIN * 9) / SPLIT;
  constexpr int NCH = KTOT / 64;
  __shared__ __align__(16) unsigned short Xs[2][64][64];
  __shared__ __align__(16) unsigned short Wsh[3][64][64];
  __shared__ int pb[64], pyA[64], pxA[64];
  const int tid = threadIdx.x;
  const int oc0 = blockIdx.y * 64, px0 = blockIdx.x * 64;
  const int spl = blockIdx.z;
  const int kg0 = spl * KTOT;
  if (tid < 64) {
    int p = px0 + tid;
    if (p > NPX - 1) p = NPX - 1;
    int hw = HOUT * WOUT;
    pb[tid] = p / hw;
    int r = p % hw;
    pyA[tid] = r / WOUT;
    pxA[tid] = r % WOUT;
  }
  f32x4 acc[4] = {};
  const int l = tid & 63, wv = tid >> 6;
  const int lr = l & 15, lh = l >> 4;
  __syncthreads();
  for (int ch = 0; ch < NCH; ++ch) {
    const int kbase = kg0 + ch * 64;
    #pragma unroll
    for (int j = 0; j < 2; ++j) {
      int c = tid + 256 * j;
      int oc = c >> 3, koct = c & 7;
      const float* wp = wsrc + (size_t)(oc0 + oc) * (CIN * 9) + kbase + koct * 8;
      float vv[8];
      *(float4*)&vv[0] = *(const float4*)wp;
      *(float4*)&vv[4] = *(const float4*)(wp + 4);
      short8m ph, pm, pl2;
      #pragma unroll
      for (int i = 0; i < 8; ++i) {
        unsigned short hb = bf16_trunc(vv[i]);
        float r = vv[i] - bf16_tof(hb);
        unsigned short mb = bf16_rte(r);
        float r2 = r - bf16_tof(mb);
        unsigned short lb = bf16_rte(r2);
        ph[i] = (short)hb; pm[i] = (short)mb; pl2[i] = (short)lb;
      }
      *ldsPtr(&Wsh[0][0][0], oc, koct * 16) = ph;
      *ldsPtr(&Wsh[1][0][0], oc, koct * 16) = pm;
      *ldsPtr(&Wsh[2][0][0], oc, koct * 16) = pl2;
    }
    #pragma unroll
    for (int j = 0; j < 2; ++j) {
      int c = tid + 256 * j;
      int px = c & 63, koct = c >> 6;
      int pbv = pb[px], py = pyA[px], pxv = pxA[px];
      float vv[8];
      #pragma unroll
      for (int i = 0; i < 8; ++i) {
        int k = kbase + koct * 8 + i;
        int ci = k / 9, tap = k - ci * 9;
        int iy = py * 2 - 1 + tap / 3, ix = pxv * 2 - 1 + (tap % 3);
        float v = 0.f;
        if ((unsigned)iy < (unsigned)HIN && (unsigned)ix < (unsigned)WIN)
          v = x[(((size_t)pbv * CIN + ci) * HIN + iy) * WIN + ix];
        vv[i] = v;
      }
      short8m ph, pm;
      #pragma unroll
      for (int i = 0; i < 8; ++i) {
        unsigned short hb = bf16_trunc(vv[i]);
        unsigned short mb = bf16_rte(vv[i] - bf16_tof(hb));
        ph[i] = (short)hb; pm[i] = (short)mb;
      }
      *ldsPtr(&Xs[0][0][0], px, koct * 16) = ph;
      *ldsPtr(&Xs[1][0][0], px, koct * 16) = pm;
    }
    __syncthreads();
    #pragma unroll
    for (int ks = 0; ks < 2; ++ks) {
      const int kbyte = ks * 64 + lh * 16;
      short8m aH = *ldsPtr(&Wsh[0][0][0], wv * 16 + lr, kbyte);
      short8m aM = *ldsPtr(&Wsh[1][0][0], wv * 16 + lr, kbyte);
      short8m aL = *ldsPtr(&Wsh[2][0][0], wv * 16 + lr, kbyte);
      #pragma unroll
      for (int g = 0; g < 4; ++g) {
        short8m bH = *ldsPtr(&Xs[0][0][0], g * 16 + lr, kbyte);
        short8m bM = *ldsPtr(&Xs[1][0][0], g * 16 + lr, kbyte);
        acc[g] = __builtin_amdgcn_mfma_f32_16x16x32_bf16(aH, bH, acc[g], 0, 0, 0);
        acc[g] = __builtin_amdgcn_mfma_f32_16x16x32_bf16(aH, bM, acc[g], 0, 0, 0);
        acc[g] = __builtin_amdgcn_mfma_f32_16x16x32_bf16(aM, bH, acc[g], 0, 0, 0);
        acc[g] = __builtin_amdgcn_mfma_f32_16x16x32_bf16(aM, bM, acc[g], 0, 0, 0);
        acc[g] = __builtin_amdgcn_mfma_f32_16x16x32_bf16(aL, bH, acc[g], 0, 0, 0);
      }
    }
    __syncthreads();
  }
  const size_t N = (size_t)4 * COUT * HOUT * WOUT;
  #pragma unroll
  for (int g = 0; g < 4; ++g) {
    int pxl = g * 16 + lr;
    int pidx = px0 + pxl;
    if (pidx < NPX) {
      #pragma unroll
      for (int r = 0; r < 4; ++r) {
        int ocl = wv * 16 + lh * 4 + r;
        part[(size_t)spl * N +
             (((size_t)pb[pxl] * COUT + (oc0 + ocl)) * HOUT + pyA[pxl]) * WOUT + pxA[pxl]] =
            acc[g][r];
      }
    }
  }
}

extern "C" void kernel_launch(void* const* d_in, const int* in_sizes, int n_in,
                              void* d_out, int out_size, void* d_ws, size_t ws_size,
                              hipStream_t stream) {
  const float* img = (const float*)d_in[0];
  const float* target = (const float*)d_in[1];
  const float* gw0 = (const float*)d_in[2];
  const float* gw1 = (const float*)d_in[3];
  const float* gw2 = (const float*)d_in[4];
  const float* gw3 = (const float*)d_in[5];
  const float* gfw = (const float*)d_in[6];
  const float* gfb = (const float*)d_in[7];
  const float* lw0 = (const float*)d_in[8];
  const float* lw1 = (const float*)d_in[9];
  const float* lw2 = (const float*)d_in[10];
  const float* lw3 = (const float*)d_in[11];
  const float* lfw = (const float*)d_in[12];
  const float* lfb = (const float*)d_in[13];
  const float* fw = (const float*)d_in[14];
  const float* fb = (const float*)d_in[15];
  float* out = (float*)d_out;
  float* ws = (float*)d_ws;

  float* c1 = ws;                    // 802816   [4,64,56,56]
  float* c2 = c1 + 802816;           // 1605632  [4,512,28,28]
  float* c3 = c2 + 1605632;          // 802816   [4,1024,14,14]
  float* c4 = c3 + 802816;           // 401408   [4,2048,7,7]
  float* poolg = c4 + 401408;        // 8192
  float* pooll = poolg + 8192;       // 8192
  float* hm7 = pooll + 8192;         // 196
  float* hmr = hm7 + 196;            // 196
  float* bbox = hmr + 196;           // 16
  float* patch = ws + 3629568;       // 602112 (fallback path only)

  // TIER1 layout (r23): part 3.2M floats @4231680, Xg @7442944 (3.84M ushorts/plane)
  float* part1 = ws + 4231680;
  float* Wp1 = part1 + 2800000;
  unsigned short* XgH1 = (unsigned short*)(ws + 7442944);
  unsigned short* XgM1 = XgH1 + 3840000;
  // TIER2 layout (r24): part @4231680 (6.42M floats), Xg @10654208 (4.2M ushorts/plane)
  float* part2 = ws + 4231680;
  unsigned short* XgH2 = (unsigned short*)(ws + 10654208);
  unsigned short* XgM2 = XgH2 + 4200448;

  const bool tier2 = ws_size >= (size_t)59419648;
  const bool fast = ws_size >= (size_t)45131776;

  dim3 g7(13, 256);
  const int rg2 = 2048, rg3 = 2048, rg4 = 1568;

  for (int pass = 0; pass < 2; ++pass) {
    const float* w0 = pass ? lw0 : gw0;
    const float* w1 = pass ? lw1 : gw1;
    const float* w2 = pass ? lw2 : gw2;
    const float* w3 = pass ? lw3 : gw3;
    const float* fwp = pass ? lfw : gfw;
    const float* fbp = pass ? lfb : gfb;
    const float* inp = pass ? (fast ? (out + 169) : patch) : img;
    float* pool = pass ? pooll : poolg;
    float* outp = pass ? (out + 57) : (out + 1);

    if (tier2) {
      float* part = part2;
      unsigned short* XgH = XgH2;
      unsigned short* XgM = XgM2;
      float* Wp = part2;   // conv7-time only; part region free then
      k_padw<<<48, 256, 0, stream>>>(w0, Wp, 147, 192, 64);
      k_im2col<3, 224, 224, 56, 56, 7, 7, 4, 3, 192, 64><<<1176, 256, 0, stream>>>(inp, XgH, XgM);
      k_gemm<64, 56, 56, 192, 1, 64, 64><<<196, 256, 0, stream>>>(XgH, XgM, Wp, c1);
      k_im2col<64, 56, 56, 28, 28, 3, 3, 2, 1, 576, 64><<<882, 256, 0, stream>>>(c1, XgH, XgM);
      k_gemm<512, 28, 28, 576, 1, 128, 64><<<196, 512, 0, stream>>>(XgH, XgM, w1, c2);
      k_im2col<512, 28, 28, 14, 14, 3, 3, 2, 1, 4608, 128><<<2016, 256, 0, stream>>>(c2, XgH, XgM);
      k_gemm<1024, 14, 14, 4608, 8, 128, 128><<<448, 512, 0, stream>>>(XgH, XgM, w2, part);
      k_red<8><<<rg3, 256, 0, stream>>>(part, c3, 802816);
      k_im2col<1024, 14, 14, 7, 7, 3, 3, 2, 1, 9216, 128><<<1152, 256, 0, stream>>>(c3, XgH, XgM);
      k_gemm<2048, 7, 7, 9216, 16, 128, 128><<<512, 512, 0, stream>>>(XgH, XgM, w3, part);
      k_red<16><<<rg4, 256, 0, stream>>>(part, c4, 401408);
    } else if (fast) {
      float* part = part1;
      unsigned short* XgH = XgH1;
      unsigned short* XgM = XgM1;
      float* Wp = Wp1;
      k_padw<<<48, 256, 0, stream>>>(w0, Wp, 147, 192, 64);
      k_im2col<3, 224, 224, 56, 56, 7, 7, 4, 3, 192, 64><<<1176, 256, 0, stream>>>(inp, XgH, XgM);
      k_gemm<64, 56, 56, 192, 1, 64, 64><<<196, 256, 0, stream>>>(XgH, XgM, Wp, c1);
      k_im2col<64, 56, 56, 28, 28, 3, 3, 2, 1, 576, 64><<<882, 256, 0, stream>>>(c1, XgH, XgM);
      k_gemm<512, 28, 28, 576, 1, 128, 64><<<196, 512, 0, stream>>>(XgH, XgM, w1, c2);
      k_im2col<512, 28, 28, 14, 14, 3, 3, 2, 1, 4608, 64><<<1872, 256, 0, stream>>>(c2, XgH, XgM);
      k_gemm<1024, 14, 14, 4608, 4, 128, 64><<<416, 512, 0, stream>>>(XgH, XgM, w2, part);
      k_red<4><<<rg3, 256, 0, stream>>>(part, c3, 802816);
      k_im2col<1024, 14, 14, 7, 7, 3, 3, 2, 1, 9216, 64><<<1152, 256, 0, stream>>>(c3, XgH, XgM);
      k_gemm<2048, 7, 7, 9216, 8, 128, 64><<<512, 512, 0, stream>>>(XgH, XgM, w3, part);
      k_red<8><<<rg4, 256, 0, stream>>>(part, c4, 401408);
    } else {
      float* part = part1;
      k_conv7<<<g7, 256, 0, stream>>>(inp, w0, c1);
      k_convm<64, 56, 56, 512, 28, 28, 1><<<dim3(49, 8, 1), 256, 0, stream>>>(c1, w1, part);
      k_red<1><<<rg2, 256, 0, stream>>>(part, c2, 1605632);
      k_convm<512, 28, 28, 1024, 14, 14, 4><<<dim3(13, 16, 4), 256, 0, stream>>>(c2, w2, part);
      k_red<4><<<rg3, 256, 0, stream>>>(part, c3, 802816);
      k_convm<1024, 14, 14, 2048, 7, 7, 8><<<dim3(4, 32, 8), 256, 0, stream>>>(c3, w3, part);
      k_red<8><<<rg4, 256, 0, stream>>>(part, c4, 401408);
    }
    k_pool<<<32, 256, 0, stream>>>(c4, pool);
    k_fcsig<<<56, 256, 0, stream>>>(pool, fwp, fbp, outp);

    if (pass == 0) {
      k_hm7a<<<196, 256, 0, stream>>>(c4, hmr);
      k_hm7b<<<4, 64, 0, stream>>>(hmr, hm7);
      k_ccl<<<4, CTH, 0, stream>>>(hm7, bbox);
      k_sample<<<2352, 256, 0, stream>>>(img, bbox, out + 169);
      if (!fast) k_sample<<<2352, 256, 0, stream>>>(img, bbox, patch);
    }
  }
  // fusion FC (parallel) + loss (tiny)
  k_fcsig2<<<56, 256, 0, stream>>>(poolg, pooll, fw, fb, out + 113);
  k_loss<<<1, 64, 0, stream>>>(target, out);
}

// Round 27
// 319.731 us; speedup vs baseline: 1.1349x; 1.0262x over previous
//
#include <hip/hip_runtime.h>
#include <math.h>

typedef __attribute__((ext_vector_type(8))) short short8m;   // 8 bf16 (4 VGPRs)
typedef __attribute__((ext_vector_type(4))) float f32x4;

__device__ inline unsigned short bf16_trunc(float f) {
  return (unsigned short)(__float_as_uint(f) >> 16);
}
__device__ inline unsigned short bf16_rte(float f) {
  unsigned u = __float_as_uint(f);
  u += 0x7fffu + ((u >> 16) & 1u);
  return (unsigned short)(u >> 16);
}
__device__ inline float bf16_tof(unsigned short h) {
  return __uint_as_float(((unsigned)h) << 16);
}
// LDS XOR-swizzle for W tiles: row pitch 128B; byte ^= ((row&7)<<4) -> conflict-free b128 r/w
__device__ inline short8m* ldsPtr(unsigned short* base, int row, int byteInRow) {
  int off = (row * 128 + byteInRow) ^ ((row & 7) << 4);
  return (short8m*)((char*)base + off);
}
__device__ inline void gload16_lds(const void* g, void* d) {
  __builtin_amdgcn_global_load_lds((const __attribute__((address_space(1))) unsigned int*)g,
                                   (__attribute__((address_space(3))) unsigned int*)d, 16, 0, 0);
}

// ---------------- conv 7x7 direct (fallback path only) ----------------
__global__ __launch_bounds__(256) void k_conv7(const float* __restrict__ x,
                                               const float* __restrict__ w,
                                               float* __restrict__ y) {
  __shared__ float ws[147];
  const int boc = blockIdx.y;
  const int oc = boc & 63;
  const int b = boc >> 6;
  for (int i = threadIdx.x; i < 147; i += 256) ws[i] = w[oc * 147 + i];
  __syncthreads();
  int px = blockIdx.x * 256 + threadIdx.x;
  if (px >= 56 * 56) return;
  int oy = px / 56, ox = px % 56;
  int iy0 = oy * 4 - 3, ix0 = ox * 4 - 3;
  float acc = 0.f;
  for (int c = 0; c < 3; ++c) {
    const float* xp = x + ((size_t)(b * 3 + c)) * 224 * 224;
    #pragma unroll
    for (int ky = 0; ky < 7; ++ky) {
      int iy = iy0 + ky;
      if ((unsigned)iy < 224u) {
        #pragma unroll
        for (int kx = 0; kx < 7; ++kx) {
          int ix = ix0 + kx;
          if ((unsigned)ix < 224u)
            acc += xp[iy * 224 + ix] * ws[c * 49 + ky * 7 + kx];
        }
      }
    }
  }
  y[((size_t)boc * 56 + oy) * 56 + ox] = fmaxf(acc, 0.f);
}

// ---------------- zero-pad weights along K ----------------
__global__ __launch_bounds__(256) void k_padw(const float* __restrict__ w,
                                              float* __restrict__ wp,
                                              int kreal, int ktot, int noc) {
  int i = blockIdx.x * 256 + threadIdx.x;
  if (i >= noc * ktot) return;
  int oc = i / ktot, k = i % ktot;
  wp[i] = (k < kreal) ? w[oc * kreal + k] : 0.f;
}

// ---------------- generic im2col + 2-plane bf16 split, block-tiled (PXT px per tile) ----
template <int CIN, int HIN, int WIN, int HOUT, int WOUT, int KH, int KW, int STR, int PAD,
          int KTOT, int PXT>
__global__ __launch_bounds__(256) void k_im2col(const float* __restrict__ x,
                                                unsigned short* __restrict__ XgH,
                                                unsigned short* __restrict__ XgM) {
  constexpr int NPX = 4 * HOUT * WOUT;
  constexpr int K8 = KTOT / 8;
  constexpr int KK = KH * KW;
  int u = blockIdx.x * 256 + threadIdx.x;
  int pxin = u % PXT;
  int rest = u / PXT;
  int k8 = rest % K8;
  int pxblk = rest / K8;
  int px = pxblk * PXT + pxin;
  if (px > NPX - 1) px = NPX - 1;          // pad replication
  const int hw = HOUT * WOUT;
  int pbv = px / hw;
  int r = px % hw;
  int py = r / WOUT, pxv = r % WOUT;
  short8m ph, pm;
  #pragma unroll
  for (int i = 0; i < 8; ++i) {
    int k = k8 * 8 + i;
    int ci = k / KK, tap = k - ci * KK;
    float v = 0.f;
    if (ci < CIN) {
      int iy = py * STR - PAD + tap / KW, ix = pxv * STR - PAD + (tap % KW);
      if ((unsigned)iy < (unsigned)HIN && (unsigned)ix < (unsigned)WIN)
        v = x[(((size_t)pbv * CIN + ci) * HIN + iy) * WIN + ix];
    }
    unsigned short hb = bf16_trunc(v);
    unsigned short mb = bf16_rte(v - bf16_tof(hb));
    ph[i] = (short)hb; pm[i] = (short)mb;
  }
  size_t off = (size_t)u * 8;
  *(short8m*)(XgH + off) = ph;
  *(short8m*)(XgM + off) = pm;
}

// ---------------- GEMM (r20-proven structure; OCT x PXT tile) ----------------
template <int COUT, int HOUT, int WOUT, int KTOT, int SPLIT, int OCT, int PXT>
__global__ __launch_bounds__(OCT * 4) void k_gemm(const unsigned short* __restrict__ XgH,
                                                  const unsigned short* __restrict__ XgM,
                                                  const float* __restrict__ wsrc,
                                                  float* __restrict__ part) {
  constexpr int NPX = 4 * HOUT * WOUT;
  constexpr int NPXB = (NPX + PXT - 1) / PXT;
  constexpr int NOCB = COUT / OCT;
  constexpr int NWG = NPXB * NOCB * SPLIT;
  constexpr int KCH = KTOT / SPLIT;
  constexpr int NCH = KCH / 64;
  constexpr int NTHR = OCT * 4;
  constexpr int NWAVE = NTHR / 64;
  constexpr int NG = PXT / 16;          // px groups per wave
  constexpr int SPP = PXT / 64;         // 64-lane slabs per koct per plane
  constexpr int TS = 16 * SPP;          // total slabs (both planes)
  constexpr int SLABSW = TS / NWAVE;    // slabs per wave
  __shared__ __align__(16) unsigned short XsH[PXT * 64];   // [8 koct][PXT px][8 k]
  __shared__ __align__(16) unsigned short XsM[PXT * 64];
  __shared__ __align__(16) unsigned short WsH[OCT * 64];   // swizzled [OCT oc][64 k]
  __shared__ __align__(16) unsigned short WsM[OCT * 64];
  __shared__ int pb[PXT], pyA[PXT], pxA[PXT];
  const int tid = threadIdx.x;
  const int flat = blockIdx.x;
  constexpr int q = NWG >> 3, r = NWG & 7;
  const int xc = flat & 7, of = flat >> 3;
  const int work = ((xc < r) ? xc * (q + 1) : r * (q + 1) + (xc - r) * q) + of;
  const int pxblk = work % NPXB;
  const int t2 = work / NPXB;
  const int oc0 = (t2 % NOCB) * OCT;
  const int spl = t2 / NOCB;
  if (tid < PXT) {
    int p = pxblk * PXT + tid;
    if (p > NPX - 1) p = NPX - 1;
    int hw = HOUT * WOUT;
    pb[tid] = p / hw;
    int rr = p % hw;
    pyA[tid] = rr / WOUT;
    pxA[tid] = rr % WOUT;
  }
  f32x4 acc[NG] = {};
  const int l = tid & 63, wv = tid >> 6;
  const int lr = l & 15, lh = l >> 4;
  __syncthreads();
  for (int ch = 0; ch < NCH; ++ch) {
    const int kbase = spl * KCH + ch * 64;
    const size_t tileOff = (size_t)pxblk * KTOT * PXT + (size_t)kbase * PXT;
    #pragma unroll
    for (int t = 0; t < SLABSW; ++t) {
      int ins = wv * SLABSW + t;
      int pl = ins >= (TS / 2);
      int wp = ins - pl * (TS / 2);
      int ko = wp / SPP, sp = wp % SPP;
      const unsigned short* g =
          (pl ? XgM : XgH) + tileOff + (size_t)ko * (PXT * 8) + sp * 512 + l * 8;
      unsigned short* d = (pl ? XsM : XsH) + ko * (PXT * 8) + sp * 512;
      gload16_lds(g, d);
    }
    #pragma unroll
    for (int j = 0; j < 2; ++j) {
      int c = tid + NTHR * j;
      int oc = c >> 3, koct = c & 7;
      const float* wp = wsrc + (size_t)(oc0 + oc) * KTOT + kbase + koct * 8;
      float vv[8];
      *(float4*)&vv[0] = *(const float4*)wp;
      *(float4*)&vv[4] = *(const float4*)(wp + 4);
      short8m ph, pm;
      #pragma unroll
      for (int i = 0; i < 8; ++i) {
        unsigned short hb = bf16_trunc(vv[i]);
        unsigned short mb = bf16_rte(vv[i] - bf16_tof(hb));
        ph[i] = (short)hb; pm[i] = (short)mb;
      }
      *ldsPtr(WsH, oc, koct * 16) = ph;
      *ldsPtr(WsM, oc, koct * 16) = pm;
    }
    __syncthreads();                       // drains vmcnt (global_load_lds) + lgkm
    #pragma unroll
    for (int ks = 0; ks < 2; ++ks) {
      const int kbyte = ks * 64 + lh * 16;
      short8m aH = *ldsPtr(WsH, wv * 16 + lr, kbyte);
      short8m aM = *ldsPtr(WsM, wv * 16 + lr, kbyte);
      const int xoff = (ks * 4 + lh) * (PXT * 8);
      #pragma unroll
      for (int g4 = 0; g4 < NG; ++g4) {
        short8m bH = *(const short8m*)(XsH + xoff + (g4 * 16 + lr) * 8);
        short8m bM = *(const short8m*)(XsM + xoff + (g4 * 16 + lr) * 8);
        acc[g4] = __builtin_amdgcn_mfma_f32_16x16x32_bf16(aH, bH, acc[g4], 0, 0, 0);
        acc[g4] = __builtin_amdgcn_mfma_f32_16x16x32_bf16(aH, bM, acc[g4], 0, 0, 0);
        acc[g4] = __builtin_amdgcn_mfma_f32_16x16x32_bf16(aM, bH, acc[g4], 0, 0, 0);
      }
    }
    __syncthreads();
  }
  const size_t N = (size_t)4 * COUT * HOUT * WOUT;
  #pragma unroll
  for (int g4 = 0; g4 < NG; ++g4) {
    int pxl = g4 * 16 + lr;
    int pidx = pxblk * PXT + pxl;
    if (pidx < NPX) {
      #pragma unroll
      for (int rr = 0; rr < 4; ++rr) {
        int ocl = wv * 16 + lh * 4 + rr;
        float v = acc[g4][rr];
        if (SPLIT == 1) v = fmaxf(v, 0.f);   // fused ReLU (direct output)
        part[(size_t)spl * N +
             (((size_t)pb[pxl] * COUT + (oc0 + ocl)) * HOUT + pyA[pxl]) * WOUT + pxA[pxl]] = v;
      }
    }
  }
}

// ---------------- split-K reduction + ReLU ----------------
template <int SPLIT>
__global__ __launch_bounds__(256) void k_red(const float* __restrict__ part,
                                             float* __restrict__ y, int n) {
  for (int i = blockIdx.x * 256 + threadIdx.x; i < n; i += gridDim.x * 256) {
    float s = 0.f;
    #pragma unroll
    for (int sp = 0; sp < SPLIT; ++sp) s += part[(size_t)sp * n + i];
    y[i] = fmaxf(s, 0.f);
  }
}

// ---------------- global-max-pool (7x7): one thread per (b,ch) ----------------
__global__ __launch_bounds__(256) void k_pool(const float* __restrict__ feat,
                                              float* __restrict__ pool) {
  int idx = blockIdx.x * 256 + threadIdx.x;
  if (idx >= 8192) return;
  const float* fp = feat + (size_t)idx * 49;
  float m = fp[0];
  #pragma unroll
  for (int i = 1; i < 49; ++i) m = fmaxf(m, fp[i]);
  pool[idx] = m;
}

// ---------------- FC(2048->14) + sigmoid: one block per (b,c) ----------------
__global__ __launch_bounds__(256) void k_fcsig(const float* __restrict__ pool,
                                               const float* __restrict__ fw,
                                               const float* __restrict__ fb,
                                               float* __restrict__ outp) {
  __shared__ float red[256];
  const int blk = blockIdx.x;       // b*14 + c
  const int b = blk / 14, c = blk % 14;
  const int tid = threadIdx.x;
  float s = 0.f;
  for (int k = tid; k < 2048; k += 256) s += pool[b * 2048 + k] * fw[c * 2048 + k];
  red[tid] = s;
  __syncthreads();
  for (int st = 128; st > 0; st >>= 1) {
    if (tid < st) red[tid] += red[tid + st];
    __syncthreads();
  }
  if (tid == 0) outp[b * 14 + c] = 1.f / (1.f + expf(-(red[0] + fb[c])));
}

// ---------------- fused FC(4096->14) + sigmoid for out_f ----------------
__global__ __launch_bounds__(256) void k_fcsig2(const float* __restrict__ poolg,
                                                const float* __restrict__ pooll,
                                                const float* __restrict__ fw,
                                                const float* __restrict__ fb,
                                                float* __restrict__ outp) {
  __shared__ float red[256];
  const int blk = blockIdx.x;       // b*14 + c
  const int b = blk / 14, c = blk % 14;
  const int tid = threadIdx.x;
  const float* w = fw + (size_t)c * 4096;
  float s = 0.f;
  for (int k = tid; k < 2048; k += 256) s += poolg[b * 2048 + k] * w[k];
  for (int k = tid; k < 2048; k += 256) s += pooll[b * 2048 + k] * w[2048 + k];
  red[tid] = s;
  __syncthreads();
  for (int st = 128; st > 0; st >>= 1) {
    if (tid < st) red[tid] += red[tid + st];
    __syncthreads();
  }
  if (tid == 0) outp[blk] = 1.f / (1.f + expf(-(red[0] + fb[c])));
}

// ---------------- loss: weighted BCEs ----------------
__global__ __launch_bounds__(64) void k_loss(const float* __restrict__ target,
                                             float* __restrict__ dout) {
  __shared__ float red[64];
  const int tid = threadIdx.x;
  float term = 0.f;
  if (tid < 56) {
    float t = target[tid];
    float pg = dout[1 + tid], plo = dout[57 + tid], pf = dout[113 + tid];
    auto bce1 = [&](float pp) {
      pp = fminf(fmaxf(pp, 1e-7f), 1.f - 1e-7f);
      return -(t * logf(pp) + (1.f - t) * log1pf(-pp));
    };
    term = (0.8f * bce1(pg) + 0.1f * bce1(plo) + 0.1f * bce1(pf)) * (1.f / 56.f);
  }
  red[tid] = term;
  __syncthreads();
  for (int st = 32; st > 0; st >>= 1) {
    if (tid < st) red[tid] += red[tid + st];
    __syncthreads();
  }
  if (tid == 0) dout[0] = red[0];
}

// ---------------- heatmap stage A: per-(b,cell) channel max|.| ----------------
__global__ __launch_bounds__(256) void k_hm7a(const float* __restrict__ feat,
                                              float* __restrict__ hmr) {
  __shared__ float red[256];
  const int b = blockIdx.x / 49, cell = blockIdx.x % 49;
  const int tid = threadIdx.x;
  float m = 0.f;
  for (int ch = tid; ch < 2048; ch += 256)
    m = fmaxf(m, fabsf(feat[((size_t)b * 2048 + ch) * 49 + cell]));
  red[tid] = m;
  __syncthreads();
  for (int st = 128; st > 0; st >>= 1) {
    if (tid < st) red[tid] = fmaxf(red[tid], red[tid + st]);
    __syncthreads();
  }
  if (tid == 0) hmr[b * 49 + cell] = red[0];
}

// ---------------- heatmap stage B: per-sample min-max normalize ----------------
__global__ __launch_bounds__(64) void k_hm7b(const float* __restrict__ hmr,
                                             float* __restrict__ hm7) {
  __shared__ float h[49];
  const int b = blockIdx.x, tid = threadIdx.x;
  if (tid < 49) h[tid] = hmr[b * 49 + tid];
  __syncthreads();
  if (tid == 0) {
    float mn = h[0], mx = h[0];
    for (int i = 1; i < 49; ++i) {
      mn = fminf(mn, h[i]);
      mx = fmaxf(mx, h[i]);
    }
    for (int i = 0; i < 49; ++i) hm7[b * 49 + i] = (h[i] - mn) / (mx - mn);
  }
}

// ---------------- parallel CCL: 1024 threads (16 waves -> 4/SIMD latency hiding) --------
#define MAXR 8
#define NRUNS (224 * MAXR)
#define CTH 1024
__global__ __launch_bounds__(CTH) void k_ccl(const float* __restrict__ hm7, float* __restrict__ bbox) {
  const int b = blockIdx.x, tid = threadIdx.x;
  __shared__ float h7[49];
  __shared__ short rx0[NRUNS], rx1[NRUNS];
  __shared__ short nr[224];
  __shared__ int lab[NRUNS];
  __shared__ int cnt[NRUNS], mid[NRUNS];
  __shared__ int rmn[NRUNS], rmx[NRUNS], cmn[NRUNS], cmx[NRUNS];
  __shared__ int chg;
  __shared__ int bestC[CTH], bestM[CTH], bestI[CTH];

  if (tid < 49) h7[tid] = hm7[b * 49 + tid];
  for (int i = tid; i < NRUNS; i += CTH) {
    cnt[i] = 0; mid[i] = -1;
    rmn[i] = 1 << 30; rmx[i] = -1; cmn[i] = 1 << 30; cmx[i] = -1;
    lab[i] = i;
  }
  __syncthreads();
  if (tid < 224) {
    int yy = tid;
    float py = ((float)yy + 0.5f) * (7.f / 224.f) - 0.5f;
    py = fminf(fmaxf(py, 0.f), 6.f);
    int y0 = (int)floorf(py);
    if (y0 > 5) y0 = 5;
    float fy = py - (float)y0;
    int n = 0, start = -1;
    const int segLo[6] = {0, 48, 80, 112, 144, 176};
    const int segHi[6] = {48, 80, 112, 144, 176, 224};
    #pragma unroll
    for (int s = 0; s < 6; ++s) {
      float A = h7[y0 * 7 + s], B = h7[y0 * 7 + s + 1];
      float C = h7[(y0 + 1) * 7 + s], D = h7[(y0 + 1) * 7 + s + 1];
      for (int xx = segLo[s]; xx < segHi[s]; ++xx) {
        float px = ((float)xx + 0.5f) * (7.f / 224.f) - 0.5f;
        px = fminf(fmaxf(px, 0.f), 6.f);
        float fx = px - (float)s;
        float v = (1.f - fy) * ((1.f - fx) * A + fx * B) +
                  fy * ((1.f - fx) * C + fx * D);
        bool m = v > 0.7f;
        if (m && start < 0) start = xx;
        if (!m && start >= 0) {
          if (n < MAXR) { rx0[yy * MAXR + n] = (short)start; rx1[yy * MAXR + n] = (short)(xx - 1); n++; }
          start = -1;
        }
      }
    }
    if (start >= 0 && n < MAXR) { rx0[yy * MAXR + n] = (short)start; rx1[yy * MAXR + n] = 223; n++; }
    nr[yy] = (short)n;
  }
  __syncthreads();
  int myA0[2], myA1[2];
  bool myV[2];
  #pragma unroll
  for (int j = 0; j < 2; ++j) {
    int i = tid + j * CTH;
    bool v = (i < NRUNS) && ((i & 7) < (int)nr[i >> 3]);
    myV[j] = v;
    myA0[j] = v ? (int)rx0[i] : 0;
    myA1[j] = v ? (int)rx1[i] : 0;
  }
  for (int outer = 0; outer < 128; ++outer) {
    if (tid == 0) chg = 0;
    __syncthreads();
    bool any = false;
    #pragma unroll
    for (int j = 0; j < 2; ++j) {
      if (!myV[j]) continue;
      int i = tid + j * CTH;
      int yy = i >> 3;
      int a0 = myA0[j], a1 = myA1[j];
      int ri = lab[i];
      if (yy > 0) {
        int n1 = nr[yy - 1];
        for (int kk = 0; kk < n1; ++kk) {
          int q = ((yy - 1) << 3) + kk;
          if (a0 <= rx1[q] + 1 && a1 >= rx0[q] - 1) {
            int rq = lab[q];
            if (rq < ri) { atomicMin(&lab[ri], rq); any = true; }
            else if (ri < rq) { atomicMin(&lab[rq], ri); any = true; }
          }
        }
      }
      if (yy < 223) {
        int n1 = nr[yy + 1];
        for (int kk = 0; kk < n1; ++kk) {
          int q = ((yy + 1) << 3) + kk;
          if (a0 <= rx1[q] + 1 && a1 >= rx0[q] - 1) {
            int rq = lab[q];
            if (rq < ri) { atomicMin(&lab[ri], rq); any = true; }
            else if (ri < rq) { atomicMin(&lab[rq], ri); any = true; }
          }
        }
      }
    }
    if (any) chg = 1;
    #pragma unroll
    for (int sc = 0; sc < 3; ++sc) {
      #pragma unroll
      for (int j = 0; j < 2; ++j) {
        int i = tid + j * CTH;
        if (i < NRUNS) {
          int ll = lab[i];
          int l2 = lab[ll];
          if (l2 < ll) lab[i] = l2;
        }
      }
    }
    __syncthreads();
    if (!chg) break;
  }
  for (int i = tid; i < NRUNS; i += CTH) {
    int yy = i >> 3, k = i & 7;
    if (k >= (int)nr[yy]) continue;
    int r = lab[i];
    int a0 = rx0[i], a1 = rx1[i];
    atomicAdd(&cnt[r], a1 - a0 + 1);
    atomicMax(&mid[r], yy * 224 + a1 + 1);
    atomicMin(&rmn[r], yy);
    atomicMax(&rmx[r], yy);
    atomicMin(&cmn[r], a0);
    atomicMax(&cmx[r], a1);
  }
  __syncthreads();
  int bc = -1, bm = 0x7fffffff, bi = -1;
  for (int i = tid; i < NRUNS; i += CTH) {
    if (cnt[i] > 0 && lab[i] == i) {
      if (cnt[i] > bc || (cnt[i] == bc && mid[i] < bm)) { bc = cnt[i]; bm = mid[i]; bi = i; }
    }
  }
  bestC[tid] = bc; bestM[tid] = bm; bestI[tid] = bi;
  __syncthreads();
  for (int st = CTH / 2; st > 0; st >>= 1) {
    if (tid < st) {
      if (bestC[tid + st] > bestC[tid] ||
          (bestC[tid + st] == bestC[tid] && bestM[tid + st] < bestM[tid])) {
        bestC[tid] = bestC[tid + st]; bestM[tid] = bestM[tid + st]; bestI[tid] = bestI[tid + st];
      }
    }
    __syncthreads();
  }
  if (tid == 0) {
    int bw = bestI[0];
    float fy0, chf, fx0, cwf;
    if (bw < 0) { fy0 = 224.f; chf = 1.f; fx0 = 224.f; cwf = 1.f; }
    else {
      int dr = rmx[bw] - rmn[bw]; if (dr < 1) dr = 1;
      int dc = cmx[bw] - cmn[bw]; if (dc < 1) dc = 1;
      fy0 = (float)rmn[bw]; chf = (float)dr;
      fx0 = (float)cmn[bw]; cwf = (float)dc;
    }
    bbox[b * 4 + 0] = fy0; bbox[b * 4 + 1] = chf;
    bbox[b * 4 + 2] = fx0; bbox[b * 4 + 3] = cwf;
  }
}

// ---------------- bilinear crop-resize back to 224x224 ----------------
__global__ __launch_bounds__(256) void k_sample(const float* __restrict__ img,
                                                const float* __restrict__ bbox,
                                                float* __restrict__ patch_out) {
  int idx = blockIdx.x * 256 + threadIdx.x;
  if (idx >= 4 * 3 * 224 * 224) return;
  int b = idx / (3 * 224 * 224);
  int r = idx % (3 * 224 * 224);
  int c = r / (224 * 224);
  int p = r % (224 * 224);
  int oy = p / 224, ox = p % 224;
  float fy0 = bbox[b * 4 + 0], chf = bbox[b * 4 + 1];
  float fx0 = bbox[b * 4 + 2], cwf = bbox[b * 4 + 3];
  float gy = ((float)oy + 0.5f) * (chf / 224.f) + fy0 - 0.5f;
  float gx = ((float)ox + 0.5f) * (cwf / 224.f) + fx0 - 0.5f;
  gy = fminf(fmaxf(gy, fy0), fmaxf(fy0 + chf - 1.f, fy0));
  gx = fminf(fmaxf(gx, fx0), fmaxf(fx0 + cwf - 1.f, fx0));
  int y0 = (int)floorf(gy);
  int x0 = (int)floorf(gx);
  float fy = gy - (float)y0, fx = gx - (float)x0;
  int y0c = min(max(y0, 0), 223), y1c = min(max(y0 + 1, 0), 223);
  int x0c = min(max(x0, 0), 223), x1c = min(max(x0 + 1, 0), 223);
  const float* ip = img + ((size_t)b * 3 + c) * 224 * 224;
  float v00 = ip[y0c * 224 + x0c], v01 = ip[y0c * 224 + x1c];
  float v10 = ip[y1c * 224 + x0c], v11 = ip[y1c * 224 + x1c];
  float v = (1.f - fy) * ((1.f - fx) * v00 + fx * v01) + fy * ((1.f - fx) * v10 + fx * v11);
  patch_out[idx] = v;
}

// ---------------- fallback conv (round-11 proven path) ----------------
template <int CIN, int HIN, int WIN, int COUT, int HOUT, int WOUT, int SPLIT>
__global__ __launch_bounds__(256) void k_convm(const float* __restrict__ x,
                                               const float* __restrict__ wsrc,
                                               float* __restrict__ part) {
  constexpr int NPX = 4 * HOUT * WOUT;
  constexpr int KTOT = (CIN * 9) / SPLIT;
  constexpr int NCH = KTOT / 64;
  __shared__ __align__(16) unsigned short Xs[2][64][64];
  __shared__ __align__(16) unsigned short Wsh[3][64][64];
  __shared__ int pb[64], pyA[64], pxA[64];
  const int tid = threadIdx.x;
  const int oc0 = blockIdx.y * 64, px0 = blockIdx.x * 64;
  const int spl = blockIdx.z;
  const int kg0 = spl * KTOT;
  if (tid < 64) {
    int p = px0 + tid;
    if (p > NPX - 1) p = NPX - 1;
    int hw = HOUT * WOUT;
    pb[tid] = p / hw;
    int r = p % hw;
    pyA[tid] = r / WOUT;
    pxA[tid] = r % WOUT;
  }
  f32x4 acc[4] = {};
  const int l = tid & 63, wv = tid >> 6;
  const int lr = l & 15, lh = l >> 4;
  __syncthreads();
  for (int ch = 0; ch < NCH; ++ch) {
    const int kbase = kg0 + ch * 64;
    #pragma unroll
    for (int j = 0; j < 2; ++j) {
      int c = tid + 256 * j;
      int oc = c >> 3, koct = c & 7;
      const float* wp = wsrc + (size_t)(oc0 + oc) * (CIN * 9) + kbase + koct * 8;
      float vv[8];
      *(float4*)&vv[0] = *(const float4*)wp;
      *(float4*)&vv[4] = *(const float4*)(wp + 4);
      short8m ph, pm, pl2;
      #pragma unroll
      for (int i = 0; i < 8; ++i) {
        unsigned short hb = bf16_trunc(vv[i]);
        float r = vv[i] - bf16_tof(hb);
        unsigned short mb = bf16_rte(r);
        float r2 = r - bf16_tof(mb);
        unsigned short lb = bf16_rte(r2);
        ph[i] = (short)hb; pm[i] = (short)mb; pl2[i] = (short)lb;
      }
      *ldsPtr(&Wsh[0][0][0], oc, koct * 16) = ph;
      *ldsPtr(&Wsh[1][0][0], oc, koct * 16) = pm;
      *ldsPtr(&Wsh[2][0][0], oc, koct * 16) = pl2;
    }
    #pragma unroll
    for (int j = 0; j < 2; ++j) {
      int c = tid + 256 * j;
      int px = c & 63, koct = c >> 6;
      int pbv = pb[px], py = pyA[px], pxv = pxA[px];
      float vv[8];
      #pragma unroll
      for (int i = 0; i < 8; ++i) {
        int k = kbase + koct * 8 + i;
        int ci = k / 9, tap = k - ci * 9;
        int iy = py * 2 - 1 + tap / 3, ix = pxv * 2 - 1 + (tap % 3);
        float v = 0.f;
        if ((unsigned)iy < (unsigned)HIN && (unsigned)ix < (unsigned)WIN)
          v = x[(((size_t)pbv * CIN + ci) * HIN + iy) * WIN + ix];
        vv[i] = v;
      }
      short8m ph, pm;
      #pragma unroll
      for (int i = 0; i < 8; ++i) {
        unsigned short hb = bf16_trunc(vv[i]);
        unsigned short mb = bf16_rte(vv[i] - bf16_tof(hb));
        ph[i] = (short)hb; pm[i] = (short)mb;
      }
      *ldsPtr(&Xs[0][0][0], px, koct * 16) = ph;
      *ldsPtr(&Xs[1][0][0], px, koct * 16) = pm;
    }
    __syncthreads();
    #pragma unroll
    for (int ks = 0; ks < 2; ++ks) {
      const int kbyte = ks * 64 + lh * 16;
      short8m aH = *ldsPtr(&Wsh[0][0][0], wv * 16 + lr, kbyte);
      short8m aM = *ldsPtr(&Wsh[1][0][0], wv * 16 + lr, kbyte);
      short8m aL = *ldsPtr(&Wsh[2][0][0], wv * 16 + lr, kbyte);
      #pragma unroll
      for (int g = 0; g < 4; ++g) {
        short8m bH = *ldsPtr(&Xs[0][0][0], g * 16 + lr, kbyte);
        short8m bM = *ldsPtr(&Xs[1][0][0], g * 16 + lr, kbyte);
        acc[g] = __builtin_amdgcn_mfma_f32_16x16x32_bf16(aH, bH, acc[g], 0, 0, 0);
        acc[g] = __builtin_amdgcn_mfma_f32_16x16x32_bf16(aH, bM, acc[g], 0, 0, 0);
        acc[g] = __builtin_amdgcn_mfma_f32_16x16x32_bf16(aM, bH, acc[g], 0, 0, 0);
        acc[g] = __builtin_amdgcn_mfma_f32_16x16x32_bf16(aM, bM, acc[g], 0, 0, 0);
        acc[g] = __builtin_amdgcn_mfma_f32_16x16x32_bf16(aL, bH, acc[g], 0, 0, 0);
      }
    }
    __syncthreads();
  }
  const size_t N = (size_t)4 * COUT * HOUT * WOUT;
  #pragma unroll
  for (int g = 0; g < 4; ++g) {
    int pxl = g * 16 + lr;
    int pidx = px0 + pxl;
    if (pidx < NPX) {
      #pragma unroll
      for (int r = 0; r < 4; ++r) {
        int ocl = wv * 16 + lh * 4 + r;
        part[(size_t)spl * N +
             (((size_t)pb[pxl] * COUT + (oc0 + ocl)) * HOUT + pyA[pxl]) * WOUT + pxA[pxl]] =
            acc[g][r];
      }
    }
  }
}

extern "C" void kernel_launch(void* const* d_in, const int* in_sizes, int n_in,
                              void* d_out, int out_size, void* d_ws, size_t ws_size,
                              hipStream_t stream) {
  const float* img = (const float*)d_in[0];
  const float* target = (const float*)d_in[1];
  const float* gw0 = (const float*)d_in[2];
  const float* gw1 = (const float*)d_in[3];
  const float* gw2 = (const float*)d_in[4];
  const float* gw3 = (const float*)d_in[5];
  const float* gfw = (const float*)d_in[6];
  const float* gfb = (const float*)d_in[7];
  const float* lw0 = (const float*)d_in[8];
  const float* lw1 = (const float*)d_in[9];
  const float* lw2 = (const float*)d_in[10];
  const float* lw3 = (const float*)d_in[11];
  const float* lfw = (const float*)d_in[12];
  const float* lfb = (const float*)d_in[13];
  const float* fw = (const float*)d_in[14];
  const float* fb = (const float*)d_in[15];
  float* out = (float*)d_out;
  float* ws = (float*)d_ws;

  float* c1 = ws;                    // 802816   [4,64,56,56]
  float* c2 = c1 + 802816;           // 1605632  [4,512,28,28]
  float* c3 = c2 + 1605632;          // 802816   [4,1024,14,14]
  float* c4 = c3 + 802816;           // 401408   [4,2048,7,7]
  float* poolg = c4 + 401408;        // 8192
  float* pooll = poolg + 8192;       // 8192
  float* hm7 = pooll + 8192;         // 196
  float* hmr = hm7 + 196;            // 196
  float* bbox = hmr + 196;           // 16
  float* patch = ws + 3629568;       // 602112 (fallback path only)

  // TIER1 layout (r23): part 3.2M floats @4231680, Xg @7442944 (3.84M ushorts/plane)
  float* part1 = ws + 4231680;
  float* Wp1 = part1 + 2800000;
  unsigned short* XgH1 = (unsigned short*)(ws + 7442944);
  unsigned short* XgM1 = XgH1 + 3840000;
  // TIER2 layout (r24): part @4231680 (6.42M floats), Xg @10654208 (4.2M ushorts/plane)
  float* part2 = ws + 4231680;
  unsigned short* XgH2 = (unsigned short*)(ws + 10654208);
  unsigned short* XgM2 = XgH2 + 4200448;

  const bool tier2 = ws_size >= (size_t)59419648;
  const bool fast = ws_size >= (size_t)45131776;

  dim3 g7(13, 256);
  const int rg2 = 2048, rg3 = 2048, rg4 = 1568;

  for (int pass = 0; pass < 2; ++pass) {
    const float* w0 = pass ? lw0 : gw0;
    const float* w1 = pass ? lw1 : gw1;
    const float* w2 = pass ? lw2 : gw2;
    const float* w3 = pass ? lw3 : gw3;
    const float* fwp = pass ? lfw : gfw;
    const float* fbp = pass ? lfb : gfb;
    const float* inp = pass ? (fast ? (out + 169) : patch) : img;
    float* pool = pass ? pooll : poolg;
    float* outp = pass ? (out + 57) : (out + 1);

    if (tier2) {
      float* part = part2;
      unsigned short* XgH = XgH2;
      unsigned short* XgM = XgM2;
      float* Wp = part2;   // conv7-time only; part region free then
      k_padw<<<48, 256, 0, stream>>>(w0, Wp, 147, 192, 64);
      k_im2col<3, 224, 224, 56, 56, 7, 7, 4, 3, 192, 64><<<1176, 256, 0, stream>>>(inp, XgH, XgM);
      k_gemm<64, 56, 56, 192, 1, 64, 64><<<196, 256, 0, stream>>>(XgH, XgM, Wp, c1);
      k_im2col<64, 56, 56, 28, 28, 3, 3, 2, 1, 576, 64><<<882, 256, 0, stream>>>(c1, XgH, XgM);
      k_gemm<512, 28, 28, 576, 1, 64, 64><<<392, 256, 0, stream>>>(XgH, XgM, w1, c2);
      k_im2col<512, 28, 28, 14, 14, 3, 3, 2, 1, 4608, 128><<<2016, 256, 0, stream>>>(c2, XgH, XgM);
      k_gemm<1024, 14, 14, 4608, 8, 128, 128><<<448, 512, 0, stream>>>(XgH, XgM, w2, part);
      k_red<8><<<rg3, 256, 0, stream>>>(part, c3, 802816);
      k_im2col<1024, 14, 14, 7, 7, 3, 3, 2, 1, 9216, 128><<<1152, 256, 0, stream>>>(c3, XgH, XgM);
      k_gemm<2048, 7, 7, 9216, 16, 128, 128><<<512, 512, 0, stream>>>(XgH, XgM, w3, part);
      k_red<16><<<rg4, 256, 0, stream>>>(part, c4, 401408);
    } else if (fast) {
      float* part = part1;
      unsigned short* XgH = XgH1;
      unsigned short* XgM = XgM1;
      float* Wp = Wp1;
      k_padw<<<48, 256, 0, stream>>>(w0, Wp, 147, 192, 64);
      k_im2col<3, 224, 224, 56, 56, 7, 7, 4, 3, 192, 64><<<1176, 256, 0, stream>>>(inp, XgH, XgM);
      k_gemm<64, 56, 56, 192, 1, 64, 64><<<196, 256, 0, stream>>>(XgH, XgM, Wp, c1);
      k_im2col<64, 56, 56, 28, 28, 3, 3, 2, 1, 576, 64><<<882, 256, 0, stream>>>(c1, XgH, XgM);
      k_gemm<512, 28, 28, 576, 1, 64, 64><<<392, 256, 0, stream>>>(XgH, XgM, w1, c2);
      k_im2col<512, 28, 28, 14, 14, 3, 3, 2, 1, 4608, 64><<<1872, 256, 0, stream>>>(c2, XgH, XgM);
      k_gemm<1024, 14, 14, 4608, 4, 128, 64><<<416, 512, 0, stream>>>(XgH, XgM, w2, part);
      k_red<4><<<rg3, 256, 0, stream>>>(part, c3, 802816);
      k_im2col<1024, 14, 14, 7, 7, 3, 3, 2, 1, 9216, 64><<<1152, 256, 0, stream>>>(c3, XgH, XgM);
      k_gemm<2048, 7, 7, 9216, 8, 128, 64><<<512, 512, 0, stream>>>(XgH, XgM, w3, part);
      k_red<8><<<rg4, 256, 0, stream>>>(part, c4, 401408);
    } else {
      float* part = part1;
      k_conv7<<<g7, 256, 0, stream>>>(inp, w0, c1);
      k_convm<64, 56, 56, 512, 28, 28, 1><<<dim3(49, 8, 1), 256, 0, stream>>>(c1, w1, part);
      k_red<1><<<rg2, 256, 0, stream>>>(part, c2, 1605632);
      k_convm<512, 28, 28, 1024, 14, 14, 4><<<dim3(13, 16, 4), 256, 0, stream>>>(c2, w2, part);
      k_red<4><<<rg3, 256, 0, stream>>>(part, c3, 802816);
      k_convm<1024, 14, 14, 2048, 7, 7, 8><<<dim3(4, 32, 8), 256, 0, stream>>>(c3, w3, part);
      k_red<8><<<rg4, 256, 0, stream>>>(part, c4, 401408);
    }
    k_pool<<<32, 256, 0, stream>>>(c4, pool);
    k_fcsig<<<56, 256, 0, stream>>>(pool, fwp, fbp, outp);

    if (pass == 0) {
      k_hm7a<<<196, 256, 0, stream>>>(c4, hmr);
      k_hm7b<<<4, 64, 0, stream>>>(hmr, hm7);
      k_ccl<<<4, CTH, 0, stream>>>(hm7, bbox);
      k_sample<<<2352, 256, 0, stream>>>(img, bbox, out + 169);
      if (!fast) k_sample<<<2352, 256, 0, stream>>>(img, bbox, patch);
    }
  }
  // fusion FC (parallel) + loss (tiny)
  k_fcsig2<<<56, 256, 0, stream>>>(poolg, pooll, fw, fb, out + 113);
  k_loss<<<1, 64, 0, stream>>>(target, out);
}